// Round 1
// baseline (1419.252 us; speedup 1.0000x reference)
//
#include <hip/hip_runtime.h>
#include <hip/hip_bf16.h>
#include <math.h>

// Problem constants
#define BB 2
#define CC 512
#define HH 32
#define WW 32
#define HWP 1024      // H*W
#define GG 8
#define DH 64
#define HD 8
#define WD 8
#define JJ 64         // HD*WD
#define BG 16         // BB*GG
#define EPS 1e-5f

// ---------------- K1: BN1 ----------------
__global__ void k_bn1(const float* __restrict__ x, const float* __restrict__ g,
                      const float* __restrict__ b, float* __restrict__ xn) {
    int idx = blockIdx.x * 256 + threadIdx.x;          // 1,048,576 total
    int c = (idx >> 10) & (CC - 1);
    float s = g[c] / sqrtf(1.0f + EPS);
    xn[idx] = x[idx] * s + b[c];
}

// ---------------- K2: q grouped 1x1 conv ----------------
// q[b, g*64+o, i] = sum_c xn[b, g*64+c, i] * qw[g,o,c]
__global__ void k_qconv(const float* __restrict__ xn, const float* __restrict__ qw,
                        float* __restrict__ q) {
    int o_lin = blockIdx.x;                  // b*512 + g*64 + o, 0..1023
    int i = blockIdx.y * 256 + threadIdx.x;  // 0..1023
    int b = o_lin >> 9;
    int g = (o_lin >> 6) & 7;
    int o = o_lin & 63;
    const float* wrow = qw + (g * 64 + o) * 64;
    const float* xin = xn + (size_t)(b * CC + g * 64) * HWP + i;
    float acc = 0.f;
#pragma unroll
    for (int c = 0; c < 64; c++) acc = fmaf(xin[c * HWP], wrow[c], acc);
    q[(size_t)o_lin * HWP + i] = acc;
}

// ---------------- K3: offsets (depthwise conv 6x6 s4 p1 + gelu + 1x1 + tanh) -> vgrid ----------------
// one block per (bg, hd, wd), 64 threads = channels
__global__ void k_off(const float* __restrict__ q, const float* __restrict__ dww,
                      const float* __restrict__ dwb, const float* __restrict__ pw,
                      float* __restrict__ vgrid) {
    int blk = blockIdx.x;          // bg*64 + hd*8 + wd
    int bg = blk >> 6;
    int hd = (blk >> 3) & 7;
    int wd = blk & 7;
    int ch = threadIdx.x;
    const float* qch = q + (size_t)(bg * 64 + ch) * HWP;
    float acc = 0.f;
#pragma unroll
    for (int kh = 0; kh < 6; kh++) {
        int hin = hd * 4 - 1 + kh;
        if (hin < 0 || hin >= HH) continue;
#pragma unroll
        for (int kw_ = 0; kw_ < 6; kw_++) {
            int win = wd * 4 - 1 + kw_;
            if (win < 0 || win >= WW) continue;
            acc = fmaf(qch[hin * WW + win], dww[ch * 36 + kh * 6 + kw_], acc);
        }
    }
    acc += dwb[ch];
    // exact gelu
    float ge = 0.5f * acc * (1.0f + erff(acc * 0.7071067811865475f));
    float p0 = ge * pw[ch];          // off_pw_w[0][ch]
    float p1 = ge * pw[64 + ch];     // off_pw_w[1][ch]
#pragma unroll
    for (int off = 32; off; off >>= 1) {
        p0 += __shfl_xor(p0, off);
        p1 += __shfl_xor(p1, off);
    }
    if (ch == 0) {
        float off0 = tanhf(p0) * 4.0f;
        float off1 = tanhf(p1) * 4.0f;
        float vx = (float)wd + off0;
        float vy = (float)hd + off1;
        float nx = 2.0f * vx / 7.0f - 1.0f;   // (Hd-1)=7
        float ny = 2.0f * vy / 7.0f - 1.0f;   // (Wd-1)=7
        vgrid[blk * 2] = nx;
        vgrid[blk * 2 + 1] = ny;
    }
}

// ---------------- K4: grid_sample (bilinear, zeros, align_corners=False) ----------------
// kv layout [bg][ch][j]
__global__ void k_sample(const float* __restrict__ xn, const float* __restrict__ vgrid,
                         float* __restrict__ kv) {
    int tid = blockIdx.x * 256 + threadIdx.x;   // 65536
    int bg = tid >> 12;
    int ch = (tid >> 6) & 63;
    int j = tid & 63;
    float nx = vgrid[(bg * 64 + j) * 2];
    float ny = vgrid[(bg * 64 + j) * 2 + 1];
    float gx = (nx + 1.0f) * 16.0f - 0.5f;   // Wi/2 = 16
    float gy = (ny + 1.0f) * 16.0f - 0.5f;
    float x0f = floorf(gx), y0f = floorf(gy);
    float wx = gx - x0f, wy = gy - y0f;
    int x0 = (int)x0f, y0 = (int)y0f;
    const float* im = xn + (size_t)(bg * 64 + ch) * HWP;
    float v00 = (x0 >= 0 && x0 < WW && y0 >= 0 && y0 < HH) ? im[y0 * WW + x0] : 0.f;
    float v01 = (x0 + 1 >= 0 && x0 + 1 < WW && y0 >= 0 && y0 < HH) ? im[y0 * WW + x0 + 1] : 0.f;
    float v10 = (x0 >= 0 && x0 < WW && y0 + 1 >= 0 && y0 + 1 < HH) ? im[(y0 + 1) * WW + x0] : 0.f;
    float v11 = (x0 + 1 >= 0 && x0 + 1 < WW && y0 + 1 >= 0 && y0 + 1 < HH) ? im[(y0 + 1) * WW + x0 + 1] : 0.f;
    float val = v00 * (1 - wx) * (1 - wy) + v01 * wx * (1 - wy)
              + v10 * (1 - wx) * wy + v11 * wx * wy;
    kv[tid] = val;
}

// ---------------- K5: k/v grouped 1x1 convs ----------------
// kk, vv layout [bg][j][o]
__global__ void k_kvconv(const float* __restrict__ kv, const float* __restrict__ kw,
                         const float* __restrict__ vw, float* __restrict__ kk,
                         float* __restrict__ vv) {
    int tid = blockIdx.x * 256 + threadIdx.x;   // 65536
    int bg = tid >> 12;
    int j = (tid >> 6) & 63;
    int o = tid & 63;
    int g = bg & 7;
    const float* kvp = kv + (size_t)bg * 4096 + j;   // [bg][c][j]
    const float* kwr = kw + (g * 64 + o) * 64;
    const float* vwr = vw + (g * 64 + o) * 64;
    float ak = 0.f, av = 0.f;
#pragma unroll
    for (int c = 0; c < 64; c++) {
        float t = kvp[c * 64];
        ak = fmaf(t, kwr[c], ak);
        av = fmaf(t, vwr[c], av);
    }
    kk[tid] = ak;
    vv[tid] = av;
}

// ---------------- K6: transpose cpb_w2 (128x128) so inner loop is contiguous ----------------
__global__ void k_w2t(const float* __restrict__ w2, float* __restrict__ w2t) {
    int t = blockIdx.x * 256 + threadIdx.x;  // 16384
    int kx = t >> 7, tt = t & 127;
    w2t[tt * 128 + kx] = w2[kx * 128 + tt];
}

// ---------------- K7: fused CPB bias MLP + attention ----------------
// one block per (bg, i): 16384 blocks x 64 threads (thread = j, then d)
__global__ __launch_bounds__(64) void k_attn(
    const float* __restrict__ q, const float* __restrict__ kk,
    const float* __restrict__ vv, const float* __restrict__ vgrid,
    const float* __restrict__ w1, const float* __restrict__ b1,
    const float* __restrict__ w2t, const float* __restrict__ b2,
    const float* __restrict__ w3, const float* __restrict__ b3,
    float* __restrict__ ao) {
    int blk = blockIdx.x;
    int bg = blk >> 10;       // 0..15
    int i = blk & 1023;
    int b = bg >> 3, g = bg & 7;
    int j = threadIdx.x;
    int hi = i >> 5, wi = i & 31;
    float qx = 2.0f * (float)wi / 31.0f - 1.0f;
    float qy = 2.0f * (float)hi / 31.0f - 1.0f;
    float gkx = vgrid[(bg * 64 + j) * 2];
    float gky = vgrid[(bg * 64 + j) * 2 + 1];
    float p0 = qx - gkx, p1 = qy - gky;
    float s0 = copysignf(log1pf(fabsf(p0)), p0);
    float s1 = copysignf(log1pf(fabsf(p1)), p1);

    float h1[128];
#pragma unroll
    for (int t = 0; t < 128; t++) {
        float v = fmaf(s0, w1[t], fmaf(s1, w1[128 + t], b1[t]));
        h1[t] = fmaxf(v, 0.f);
    }
    float bias = b3[0];
    for (int t = 0; t < 128; t++) {
        float h2 = b2[t];
        const float* w2row = w2t + t * 128;   // contiguous, thread-uniform
#pragma unroll
        for (int kx = 0; kx < 128; kx++) h2 = fmaf(h1[kx], w2row[kx], h2);
        bias = fmaf(fmaxf(h2, 0.f), w3[t], bias);
    }

    // sim = scale * q.k + bias
    const float* qrow = q + (size_t)(b * CC + g * 64) * HWP + i;  // stride HWP per d (uniform)
    const float* krow = kk + (size_t)(bg * 64 + j) * 64;
    float sim = 0.f;
#pragma unroll
    for (int d = 0; d < 64; d++) sim = fmaf(qrow[d * HWP], krow[d], sim);
    sim = sim * 0.125f + bias;

    // softmax over j (single wave of 64)
    float m = sim;
#pragma unroll
    for (int off = 32; off; off >>= 1) m = fmaxf(m, __shfl_xor(m, off));
    float p = expf(sim - m);
    float l = p;
#pragma unroll
    for (int off = 32; off; off >>= 1) l += __shfl_xor(l, off);
    float attn = p / l;

    __shared__ float attn_s[64];
    attn_s[j] = attn;
    __syncthreads();

    int d = j;
    float out = 0.f;
#pragma unroll
    for (int jj = 0; jj < 64; jj++)
        out = fmaf(attn_s[jj], vv[(size_t)(bg * 64 + jj) * 64 + d], out);
    ao[(size_t)(b * CC + g * 64 + d) * HWP + i] = out;
}

// ---------------- K8: out projection + residual ----------------
__global__ void k_outproj(const float* __restrict__ x, const float* __restrict__ ao,
                          const float* __restrict__ ow, const float* __restrict__ ob,
                          float* __restrict__ xo) {
    int bo = blockIdx.x;              // b*512 + o
    int b = bo >> 9, o = bo & 511;
    int i = blockIdx.y * 256 + threadIdx.x;
    const float* arow = ao + (size_t)b * CC * HWP + i;
    const float* wr = ow + o * CC;
    float acc = 0.f;
#pragma unroll 8
    for (int c = 0; c < CC; c++) acc = fmaf(arow[(size_t)c * HWP], wr[c], acc);
    xo[(size_t)bo * HWP + i] = x[(size_t)bo * HWP + i] + acc + ob[o];
}

// ---------------- K9: BN2 (into xn buffer, reused) ----------------
__global__ void k_bn2(const float* __restrict__ xo, const float* __restrict__ g,
                      const float* __restrict__ b, float* __restrict__ xn2) {
    int idx = blockIdx.x * 256 + threadIdx.x;
    int c = (idx >> 10) & (CC - 1);
    float s = g[c] / sqrtf(1.0f + EPS);
    xn2[idx] = xo[idx] * s + b[c];
}

// ---------------- K10: MLP layer 1 (512 -> 2048) + gelu ----------------
__global__ void k_mlp1(const float* __restrict__ xn2, const float* __restrict__ w1,
                       const float* __restrict__ b1, float* __restrict__ h1o) {
    int bm = blockIdx.x;              // b*2048 + m
    int b = bm >> 11, m = bm & 2047;
    int i = blockIdx.y * 256 + threadIdx.x;
    const float* xrow = xn2 + (size_t)b * CC * HWP + i;
    const float* wr = w1 + (size_t)m * CC;
    float acc = b1[m];
#pragma unroll 8
    for (int c = 0; c < CC; c++) acc = fmaf(xrow[(size_t)c * HWP], wr[c], acc);
    float ge = 0.5f * acc * (1.0f + erff(acc * 0.7071067811865475f));
    h1o[(size_t)bm * HWP + i] = ge;
}

// ---------------- K11: MLP layer 2 (2048 -> 512) + residual -> out ----------------
__global__ void k_mlp2(const float* __restrict__ xo, const float* __restrict__ h1o,
                       const float* __restrict__ w2, const float* __restrict__ b2,
                       float* __restrict__ out) {
    int bo = blockIdx.x;              // b*512 + o
    int b = bo >> 9, o = bo & 511;
    int i = blockIdx.y * 256 + threadIdx.x;
    const float* hrow = h1o + (size_t)b * 2048 * HWP + i;
    const float* wr = w2 + (size_t)o * 2048;
    float acc = 0.f;
#pragma unroll 8
    for (int m = 0; m < 2048; m++) acc = fmaf(hrow[(size_t)m * HWP], wr[m], acc);
    out[(size_t)bo * HWP + i] = xo[(size_t)bo * HWP + i] + acc + b2[o];
}

extern "C" void kernel_launch(void* const* d_in, const int* in_sizes, int n_in,
                              void* d_out, int out_size, void* d_ws, size_t ws_size,
                              hipStream_t stream) {
    const float* x      = (const float*)d_in[0];
    const float* bn1_g  = (const float*)d_in[1];
    const float* bn1_b  = (const float*)d_in[2];
    const float* bn2_g  = (const float*)d_in[3];
    const float* bn2_b  = (const float*)d_in[4];
    const float* qw     = (const float*)d_in[5];
    const float* kw     = (const float*)d_in[6];
    const float* vw     = (const float*)d_in[7];
    const float* out_w  = (const float*)d_in[8];
    const float* out_b  = (const float*)d_in[9];
    const float* off_dw_w = (const float*)d_in[10];
    const float* off_dw_b = (const float*)d_in[11];
    const float* off_pw_w = (const float*)d_in[12];
    const float* cpb_w1 = (const float*)d_in[13];
    const float* cpb_b1 = (const float*)d_in[14];
    const float* cpb_w2 = (const float*)d_in[15];
    const float* cpb_b2 = (const float*)d_in[16];
    const float* cpb_w3 = (const float*)d_in[17];
    const float* cpb_b3 = (const float*)d_in[18];
    const float* mlp_w1 = (const float*)d_in[19];
    const float* mlp_b1 = (const float*)d_in[20];
    const float* mlp_w2 = (const float*)d_in[21];
    const float* mlp_b2 = (const float*)d_in[22];

    float* ws = (float*)d_ws;
    // workspace layout (floats)
    float* xn    = ws + 0;            // 1,048,576 (reused as xn2)
    float* q     = ws + 1048576;      // 1,048,576
    float* vgrid = ws + 2097152;      // 2,048
    float* kv    = ws + 2099200;      // 65,536
    float* kk    = ws + 2164736;      // 65,536
    float* vv    = ws + 2230272;      // 65,536
    float* w2t   = ws + 2295808;      // 16,384
    float* ao    = ws + 2312192;      // 1,048,576
    float* xo    = ws + 3360768;      // 1,048,576
    float* h1o   = ws + 4409344;      // 4,194,304  (total 8,603,648 floats = 34.4 MB)

    hipLaunchKernelGGL(k_bn1, dim3(4096), dim3(256), 0, stream, x, bn1_g, bn1_b, xn);
    hipLaunchKernelGGL(k_qconv, dim3(1024, 4), dim3(256), 0, stream, xn, qw, q);
    hipLaunchKernelGGL(k_off, dim3(1024), dim3(64), 0, stream, q, off_dw_w, off_dw_b, off_pw_w, vgrid);
    hipLaunchKernelGGL(k_sample, dim3(256), dim3(256), 0, stream, xn, vgrid, kv);
    hipLaunchKernelGGL(k_kvconv, dim3(256), dim3(256), 0, stream, kv, kw, vw, kk, vv);
    hipLaunchKernelGGL(k_w2t, dim3(64), dim3(256), 0, stream, cpb_w2, w2t);
    hipLaunchKernelGGL(k_attn, dim3(16384), dim3(64), 0, stream,
                       q, kk, vv, vgrid, cpb_w1, cpb_b1, w2t, cpb_b2, cpb_w3, cpb_b3, ao);
    hipLaunchKernelGGL(k_outproj, dim3(1024, 4), dim3(256), 0, stream, x, ao, out_w, out_b, xo);
    hipLaunchKernelGGL(k_bn2, dim3(4096), dim3(256), 0, stream, xo, bn2_g, bn2_b, xn);
    hipLaunchKernelGGL(k_mlp1, dim3(4096, 4), dim3(256), 0, stream, xn, mlp_w1, mlp_b1, h1o);
    hipLaunchKernelGGL(k_mlp2, dim3(1024, 4), dim3(256), 0, stream, xo, h1o, mlp_w2, mlp_b2, (float*)d_out);
}

// Round 2
// 987.563 us; speedup vs baseline: 1.4371x; 1.4371x over previous
//
#include <hip/hip_runtime.h>
#include <hip/hip_bf16.h>
#include <math.h>

// Problem constants
#define BB 2
#define CC 512
#define HH 32
#define WW 32
#define HWP 1024      // H*W
#define GG 8
#define DH 64
#define HD 8
#define WD 8
#define JJ 64         // HD*WD
#define BG 16         // BB*GG
#define EPS 1e-5f

typedef __attribute__((ext_vector_type(8))) short short8;
typedef __attribute__((ext_vector_type(4))) float f32x4;

// RNE float -> bf16 bits
static __device__ __forceinline__ short f2bf(float x) {
    unsigned u = __builtin_bit_cast(unsigned, x);
    u += 0x7FFFu + ((u >> 16) & 1u);
    return (short)(u >> 16);
}

// ---------------- K1: BN1 ----------------
__global__ void k_bn1(const float* __restrict__ x, const float* __restrict__ g,
                      const float* __restrict__ b, float* __restrict__ xn) {
    int idx = blockIdx.x * 256 + threadIdx.x;          // 1,048,576 total
    int c = (idx >> 10) & (CC - 1);
    float s = g[c] / sqrtf(1.0f + EPS);
    xn[idx] = x[idx] * s + b[c];
}

// ---------------- K2: q grouped 1x1 conv ----------------
__global__ void k_qconv(const float* __restrict__ xn, const float* __restrict__ qw,
                        float* __restrict__ q) {
    int o_lin = blockIdx.x;                  // b*512 + g*64 + o
    int i = blockIdx.y * 256 + threadIdx.x;
    int b = o_lin >> 9;
    int g = (o_lin >> 6) & 7;
    int o = o_lin & 63;
    const float* wrow = qw + (g * 64 + o) * 64;
    const float* xin = xn + (size_t)(b * CC + g * 64) * HWP + i;
    float acc = 0.f;
#pragma unroll
    for (int c = 0; c < 64; c++) acc = fmaf(xin[c * HWP], wrow[c], acc);
    q[(size_t)o_lin * HWP + i] = acc;
}

// ---------------- K3: offsets -> vgrid ----------------
__global__ void k_off(const float* __restrict__ q, const float* __restrict__ dww,
                      const float* __restrict__ dwb, const float* __restrict__ pw,
                      float* __restrict__ vgrid) {
    int blk = blockIdx.x;          // bg*64 + hd*8 + wd
    int bg = blk >> 6;
    int hd = (blk >> 3) & 7;
    int wd = blk & 7;
    int ch = threadIdx.x;
    const float* qch = q + (size_t)(bg * 64 + ch) * HWP;
    float acc = 0.f;
#pragma unroll
    for (int kh = 0; kh < 6; kh++) {
        int hin = hd * 4 - 1 + kh;
        if (hin < 0 || hin >= HH) continue;
#pragma unroll
        for (int kw_ = 0; kw_ < 6; kw_++) {
            int win = wd * 4 - 1 + kw_;
            if (win < 0 || win >= WW) continue;
            acc = fmaf(qch[hin * WW + win], dww[ch * 36 + kh * 6 + kw_], acc);
        }
    }
    acc += dwb[ch];
    float ge = 0.5f * acc * (1.0f + erff(acc * 0.7071067811865475f));
    float p0 = ge * pw[ch];
    float p1 = ge * pw[64 + ch];
#pragma unroll
    for (int off = 32; off; off >>= 1) {
        p0 += __shfl_xor(p0, off);
        p1 += __shfl_xor(p1, off);
    }
    if (ch == 0) {
        float off0 = tanhf(p0) * 4.0f;
        float off1 = tanhf(p1) * 4.0f;
        float vx = (float)wd + off0;
        float vy = (float)hd + off1;
        float nx = 2.0f * vx / 7.0f - 1.0f;
        float ny = 2.0f * vy / 7.0f - 1.0f;
        vgrid[blk * 2] = nx;
        vgrid[blk * 2 + 1] = ny;
    }
}

// ---------------- K4: grid_sample ----------------
__global__ void k_sample(const float* __restrict__ xn, const float* __restrict__ vgrid,
                         float* __restrict__ kv) {
    int tid = blockIdx.x * 256 + threadIdx.x;   // 65536
    int bg = tid >> 12;
    int ch = (tid >> 6) & 63;
    int j = tid & 63;
    float nx = vgrid[(bg * 64 + j) * 2];
    float ny = vgrid[(bg * 64 + j) * 2 + 1];
    float gx = (nx + 1.0f) * 16.0f - 0.5f;
    float gy = (ny + 1.0f) * 16.0f - 0.5f;
    float x0f = floorf(gx), y0f = floorf(gy);
    float wx = gx - x0f, wy = gy - y0f;
    int x0 = (int)x0f, y0 = (int)y0f;
    const float* im = xn + (size_t)(bg * 64 + ch) * HWP;
    float v00 = (x0 >= 0 && x0 < WW && y0 >= 0 && y0 < HH) ? im[y0 * WW + x0] : 0.f;
    float v01 = (x0 + 1 >= 0 && x0 + 1 < WW && y0 >= 0 && y0 < HH) ? im[y0 * WW + x0 + 1] : 0.f;
    float v10 = (x0 >= 0 && x0 < WW && y0 + 1 >= 0 && y0 + 1 < HH) ? im[(y0 + 1) * WW + x0] : 0.f;
    float v11 = (x0 + 1 >= 0 && x0 + 1 < WW && y0 + 1 >= 0 && y0 + 1 < HH) ? im[(y0 + 1) * WW + x0 + 1] : 0.f;
    float val = v00 * (1 - wx) * (1 - wy) + v01 * wx * (1 - wy)
              + v10 * (1 - wx) * wy + v11 * wx * wy;
    kv[tid] = val;
}

// ---------------- K5: k/v grouped 1x1 convs ----------------
__global__ void k_kvconv(const float* __restrict__ kv, const float* __restrict__ kw,
                         const float* __restrict__ vw, float* __restrict__ kk,
                         float* __restrict__ vv) {
    int tid = blockIdx.x * 256 + threadIdx.x;   // 65536
    int bg = tid >> 12;
    int j = (tid >> 6) & 63;
    int o = tid & 63;
    int g = bg & 7;
    const float* kvp = kv + (size_t)bg * 4096 + j;   // [bg][c][j]
    const float* kwr = kw + (g * 64 + o) * 64;
    const float* vwr = vw + (g * 64 + o) * 64;
    float ak = 0.f, av = 0.f;
#pragma unroll
    for (int c = 0; c < 64; c++) {
        float t = kvp[c * 64];
        ak = fmaf(t, kwr[c], ak);
        av = fmaf(t, vwr[c], av);
    }
    kk[tid] = ak;
    vv[tid] = av;
}

// ---------------- K6: CPB bias MLP via bf16 MFMA ----------------
// rows r = (bg*1024+i)*64 + j, M = 1,048,576. Layer2 GEMM [M x 128]@[128 x 128]
// one wave per 32-row pair-tile (two 16x16x32 M-tiles sharing B-frags).
// grid 2048 x 256 threads (4 waves), NITER=4: 2048*4*4 pairs * 32 rows = 1M.
__global__ __launch_bounds__(256) void k_cpb(
    const float* __restrict__ vgrid,
    const float* __restrict__ w1, const float* __restrict__ b1,
    const float* __restrict__ w2, const float* __restrict__ b2,
    const float* __restrict__ w3, const float* __restrict__ b3,
    float* __restrict__ bias) {
    __shared__ __align__(16) short w2fs[16384];   // 32 KB: B-frags [nt*4+kc][lane][jj]
    int tid = threadIdx.x;
    // stage W2 into B-fragment order (coalesced global read, scattered LDS b16 write)
    for (int idx = tid; idx < 16384; idx += 256) {
        int k = idx >> 7, n = idx & 127;
        int dest = ((((n >> 4) * 4 + (k >> 5)) * 64) + (((k >> 3) & 3) * 16) + (n & 15)) * 8 + (k & 7);
        w2fs[dest] = f2bf(w2[idx]);
    }
    __syncthreads();

    int lane = tid & 63;
    int wv = tid >> 6;
    int l15 = lane & 15;
    int quad = lane >> 4;

    // per-lane hoisted coefficients: k-set = kc*32 + quad*8 + jj
    float cu[4][8], cv[4][8], cc[4][8];
#pragma unroll
    for (int kc = 0; kc < 4; kc++) {
        int kb = kc * 32 + quad * 8;
#pragma unroll
        for (int jj = 0; jj < 8; jj++) {
            cu[kc][jj] = w1[kb + jj];
            cv[kc][jj] = w1[128 + kb + jj];
            cc[kc][jj] = b1[kb + jj];
        }
    }
    float b2v[8], w3v[8];
#pragma unroll
    for (int nt = 0; nt < 8; nt++) {
        b2v[nt] = b2[nt * 16 + l15];
        w3v[nt] = w3[nt * 16 + l15];
    }
    float bias3 = b3[0];

    for (int it = 0; it < 4; it++) {
        int p = (blockIdx.x * 4 + it) * 4 + wv;       // pair index 0..32767
        int bg = p >> 11;
        int i = (p >> 1) & 1023;
        int jbase = (p & 1) * 32;
        int hi = i >> 5, wi = i & 31;
        float qx = 2.0f * (float)wi / 31.0f - 1.0f;
        float qy = 2.0f * (float)hi / 31.0f - 1.0f;

        // tile0: j = jbase + l15 ; tile1: +16
        int jA = jbase + l15;
        float gkxA = vgrid[(bg * 64 + jA) * 2];
        float gkyA = vgrid[(bg * 64 + jA) * 2 + 1];
        float gkxB = vgrid[(bg * 64 + jA + 16) * 2];
        float gkyB = vgrid[(bg * 64 + jA + 16) * 2 + 1];
        float p0 = qx - gkxA, p1 = qy - gkyA;
        float s0a = copysignf(log1pf(fabsf(p0)), p0);
        float s1a = copysignf(log1pf(fabsf(p1)), p1);
        p0 = qx - gkxB; p1 = qy - gkyB;
        float s0b = copysignf(log1pf(fabsf(p0)), p0);
        float s1b = copysignf(log1pf(fabsf(p1)), p1);

        f32x4 acc0[8], acc1[8];
#pragma unroll
        for (int nt = 0; nt < 8; nt++) {
            acc0[nt] = (f32x4){0.f, 0.f, 0.f, 0.f};
            acc1[nt] = (f32x4){0.f, 0.f, 0.f, 0.f};
        }

#pragma unroll
        for (int kc = 0; kc < 4; kc++) {
            short8 a0, a1;
#pragma unroll
            for (int jj = 0; jj < 8; jj++) {
                float h = fmaf(s0a, cu[kc][jj], fmaf(s1a, cv[kc][jj], cc[kc][jj]));
                a0[jj] = f2bf(fmaxf(h, 0.f));
                h = fmaf(s0b, cu[kc][jj], fmaf(s1b, cv[kc][jj], cc[kc][jj]));
                a1[jj] = f2bf(fmaxf(h, 0.f));
            }
#pragma unroll
            for (int nt = 0; nt < 8; nt++) {
                short8 bf = *(const short8*)(w2fs + (((nt * 4 + kc) * 64) + lane) * 8);
                acc0[nt] = __builtin_amdgcn_mfma_f32_16x16x32_bf16(a0, bf, acc0[nt], 0, 0, 0);
                acc1[nt] = __builtin_amdgcn_mfma_f32_16x16x32_bf16(a1, bf, acc1[nt], 0, 0, 0);
            }
        }

        // epilogue: relu(h2+b2)*w3, reduce over 128 cols (8 nt in-lane + 16-lane butterfly)
        int t0 = p * 2;
#pragma unroll
        for (int tt = 0; tt < 2; tt++) {
            float partial[4] = {0.f, 0.f, 0.f, 0.f};
#pragma unroll
            for (int nt = 0; nt < 8; nt++) {
                f32x4 a = tt ? acc1[nt] : acc0[nt];
#pragma unroll
                for (int r = 0; r < 4; r++) {
                    float h2 = a[r] + b2v[nt];
                    partial[r] = fmaf(fmaxf(h2, 0.f), w3v[nt], partial[r]);
                }
            }
#pragma unroll
            for (int m = 1; m <= 8; m <<= 1) {
#pragma unroll
                for (int r = 0; r < 4; r++) partial[r] += __shfl_xor(partial[r], m);
            }
            if (l15 == 0) {
                f32x4 outv = {partial[0] + bias3, partial[1] + bias3,
                              partial[2] + bias3, partial[3] + bias3};
                *(f32x4*)(bias + (t0 + tt) * 16 + quad * 4) = outv;
            }
        }
    }
}

// ---------------- K7: attention (bias precomputed) ----------------
// one block per (bg, i): 16384 blocks x 64 threads
__global__ __launch_bounds__(64) void k_attn(
    const float* __restrict__ q, const float* __restrict__ kk,
    const float* __restrict__ vv, const float* __restrict__ bias,
    float* __restrict__ ao) {
    __shared__ float ks[64 * 65];
    __shared__ float attn_s[64];
    int blk = blockIdx.x;
    int bg = blk >> 10;
    int i = blk & 1023;
    int b = bg >> 3, g = bg & 7;
    int j = threadIdx.x;

    // stage K tile (64x64) into LDS, pad-65 for conflict-free strided reads
    for (int idx = j; idx < 4096; idx += 64)
        ks[(idx >> 6) * 65 + (idx & 63)] = kk[bg * 4096 + idx];
    __syncthreads();

    const float* qrow = q + (size_t)(b * CC + g * 64) * HWP + i;  // uniform
    float sim = 0.f;
#pragma unroll
    for (int d = 0; d < 64; d++) sim = fmaf(qrow[d * HWP], ks[j * 65 + d], sim);
    sim = sim * 0.125f + bias[(size_t)blk * 64 + j];

    float m = sim;
#pragma unroll
    for (int off = 32; off; off >>= 1) m = fmaxf(m, __shfl_xor(m, off));
    float p = expf(sim - m);
    float l = p;
#pragma unroll
    for (int off = 32; off; off >>= 1) l += __shfl_xor(l, off);
    attn_s[j] = p / l;
    __syncthreads();

    int d = j;
    float out = 0.f;
#pragma unroll
    for (int jj = 0; jj < 64; jj++)
        out = fmaf(attn_s[jj], vv[(size_t)(bg * 64 + jj) * 64 + d], out);
    ao[(size_t)(b * CC + g * 64 + d) * HWP + i] = out;
}

// ---------------- K8: out projection + residual ----------------
__global__ void k_outproj(const float* __restrict__ x, const float* __restrict__ ao,
                          const float* __restrict__ ow, const float* __restrict__ ob,
                          float* __restrict__ xo) {
    int bo = blockIdx.x;              // b*512 + o
    int b = bo >> 9, o = bo & 511;
    int i = blockIdx.y * 256 + threadIdx.x;
    const float* arow = ao + (size_t)b * CC * HWP + i;
    const float* wr = ow + o * CC;
    float acc = 0.f;
#pragma unroll 8
    for (int c = 0; c < CC; c++) acc = fmaf(arow[(size_t)c * HWP], wr[c], acc);
    xo[(size_t)bo * HWP + i] = x[(size_t)bo * HWP + i] + acc + ob[o];
}

// ---------------- K9: BN2 ----------------
__global__ void k_bn2(const float* __restrict__ xo, const float* __restrict__ g,
                      const float* __restrict__ b, float* __restrict__ xn2) {
    int idx = blockIdx.x * 256 + threadIdx.x;
    int c = (idx >> 10) & (CC - 1);
    float s = g[c] / sqrtf(1.0f + EPS);
    xn2[idx] = xo[idx] * s + b[c];
}

// ---------------- K10: MLP layer 1 (512 -> 2048) + gelu ----------------
__global__ void k_mlp1(const float* __restrict__ xn2, const float* __restrict__ w1,
                       const float* __restrict__ b1, float* __restrict__ h1o) {
    int bm = blockIdx.x;              // b*2048 + m
    int b = bm >> 11, m = bm & 2047;
    int i = blockIdx.y * 256 + threadIdx.x;
    const float* xrow = xn2 + (size_t)b * CC * HWP + i;
    const float* wr = w1 + (size_t)m * CC;
    float acc = b1[m];
#pragma unroll 8
    for (int c = 0; c < CC; c++) acc = fmaf(xrow[(size_t)c * HWP], wr[c], acc);
    float ge = 0.5f * acc * (1.0f + erff(acc * 0.7071067811865475f));
    h1o[(size_t)bm * HWP + i] = ge;
}

// ---------------- K11: MLP layer 2 (2048 -> 512) + residual -> out ----------------
__global__ void k_mlp2(const float* __restrict__ xo, const float* __restrict__ h1o,
                       const float* __restrict__ w2, const float* __restrict__ b2,
                       float* __restrict__ out) {
    int bo = blockIdx.x;              // b*512 + o
    int b = bo >> 9, o = bo & 511;
    int i = blockIdx.y * 256 + threadIdx.x;
    const float* hrow = h1o + (size_t)b * 2048 * HWP + i;
    const float* wr = w2 + (size_t)o * 2048;
    float acc = 0.f;
#pragma unroll 8
    for (int m = 0; m < 2048; m++) acc = fmaf(hrow[(size_t)m * HWP], wr[m], acc);
    out[(size_t)bo * HWP + i] = xo[(size_t)bo * HWP + i] + acc + b2[o];
}

extern "C" void kernel_launch(void* const* d_in, const int* in_sizes, int n_in,
                              void* d_out, int out_size, void* d_ws, size_t ws_size,
                              hipStream_t stream) {
    const float* x      = (const float*)d_in[0];
    const float* bn1_g  = (const float*)d_in[1];
    const float* bn1_b  = (const float*)d_in[2];
    const float* bn2_g  = (const float*)d_in[3];
    const float* bn2_b  = (const float*)d_in[4];
    const float* qw     = (const float*)d_in[5];
    const float* kw     = (const float*)d_in[6];
    const float* vw     = (const float*)d_in[7];
    const float* out_w  = (const float*)d_in[8];
    const float* out_b  = (const float*)d_in[9];
    const float* off_dw_w = (const float*)d_in[10];
    const float* off_dw_b = (const float*)d_in[11];
    const float* off_pw_w = (const float*)d_in[12];
    const float* cpb_w1 = (const float*)d_in[13];
    const float* cpb_b1 = (const float*)d_in[14];
    const float* cpb_w2 = (const float*)d_in[15];
    const float* cpb_b2 = (const float*)d_in[16];
    const float* cpb_w3 = (const float*)d_in[17];
    const float* cpb_b3 = (const float*)d_in[18];
    const float* mlp_w1 = (const float*)d_in[19];
    const float* mlp_b1 = (const float*)d_in[20];
    const float* mlp_w2 = (const float*)d_in[21];
    const float* mlp_b2 = (const float*)d_in[22];

    float* ws = (float*)d_ws;
    // workspace layout (floats)
    float* xn    = ws + 0;            // 1,048,576 (reused as xn2)
    float* q     = ws + 1048576;      // 1,048,576
    float* vgrid = ws + 2097152;      // 2,048
    float* kv    = ws + 2099200;      // 65,536
    float* kk    = ws + 2164736;      // 65,536
    float* vv    = ws + 2230272;      // 65,536
    float* ao    = ws + 2312192;      // 1,048,576
    float* xo    = ws + 3360768;      // 1,048,576
    float* h1o   = ws + 4409344;      // 4,194,304
    float* biasb = h1o;               // 1,048,576 — aliases h1o start: bias fully
                                      // consumed by k_attn before k_mlp1 writes h1o
                                      // (same-stream ordering)

    hipLaunchKernelGGL(k_bn1, dim3(4096), dim3(256), 0, stream, x, bn1_g, bn1_b, xn);
    hipLaunchKernelGGL(k_qconv, dim3(1024, 4), dim3(256), 0, stream, xn, qw, q);
    hipLaunchKernelGGL(k_off, dim3(1024), dim3(64), 0, stream, q, off_dw_w, off_dw_b, off_pw_w, vgrid);
    hipLaunchKernelGGL(k_sample, dim3(256), dim3(256), 0, stream, xn, vgrid, kv);
    hipLaunchKernelGGL(k_kvconv, dim3(256), dim3(256), 0, stream, kv, kw, vw, kk, vv);
    hipLaunchKernelGGL(k_cpb, dim3(2048), dim3(256), 0, stream,
                       vgrid, cpb_w1, cpb_b1, cpb_w2, cpb_b2, cpb_w3, cpb_b3, biasb);
    hipLaunchKernelGGL(k_attn, dim3(16384), dim3(64), 0, stream, q, kk, vv, biasb, ao);
    hipLaunchKernelGGL(k_outproj, dim3(1024, 4), dim3(256), 0, stream, x, ao, out_w, out_b, xo);
    hipLaunchKernelGGL(k_bn2, dim3(4096), dim3(256), 0, stream, xo, bn2_g, bn2_b, xn);
    hipLaunchKernelGGL(k_mlp1, dim3(4096, 4), dim3(256), 0, stream, xn, mlp_w1, mlp_b1, h1o);
    hipLaunchKernelGGL(k_mlp2, dim3(1024, 4), dim3(256), 0, stream, xo, h1o, mlp_w2, mlp_b2, (float*)d_out);
}

// Round 3
// 394.049 us; speedup vs baseline: 3.6017x; 2.5062x over previous
//
#include <hip/hip_runtime.h>
#include <hip/hip_bf16.h>
#include <math.h>

// Problem constants
#define BB 2
#define CC 512
#define HH 32
#define WW 32
#define HWP 1024      // H*W
#define GG 8
#define DH 64
#define HD 8
#define WD 8
#define JJ 64         // HD*WD
#define BG 16         // BB*GG
#define EPS 1e-5f

typedef __attribute__((ext_vector_type(8))) short short8;
typedef __attribute__((ext_vector_type(4))) short s16x4;
typedef __attribute__((ext_vector_type(4))) float f32x4;
typedef __attribute__((ext_vector_type(4))) unsigned short u16x4;

// RNE float -> bf16 bits
static __device__ __forceinline__ short f2bf(float x) {
    unsigned u = __builtin_bit_cast(unsigned, x);
    u += 0x7FFFu + ((u >> 16) & 1u);
    return (short)(u >> 16);
}

// ---------------- K1: BN1 ----------------
__global__ void k_bn1(const float* __restrict__ x, const float* __restrict__ g,
                      const float* __restrict__ b, float* __restrict__ xn) {
    int idx = blockIdx.x * 256 + threadIdx.x;          // 1,048,576 total
    int c = (idx >> 10) & (CC - 1);
    float s = g[c] / sqrtf(1.0f + EPS);
    xn[idx] = x[idx] * s + b[c];
}

// ---------------- K2: q grouped 1x1 conv ----------------
__global__ void k_qconv(const float* __restrict__ xn, const float* __restrict__ qw,
                        float* __restrict__ q) {
    int o_lin = blockIdx.x;                  // b*512 + g*64 + o
    int i = blockIdx.y * 256 + threadIdx.x;
    int b = o_lin >> 9;
    int g = (o_lin >> 6) & 7;
    int o = o_lin & 63;
    const float* wrow = qw + (g * 64 + o) * 64;
    const float* xin = xn + (size_t)(b * CC + g * 64) * HWP + i;
    float acc = 0.f;
#pragma unroll
    for (int c = 0; c < 64; c++) acc = fmaf(xin[c * HWP], wrow[c], acc);
    q[(size_t)o_lin * HWP + i] = acc;
}

// ---------------- K3: offsets -> vgrid ----------------
__global__ void k_off(const float* __restrict__ q, const float* __restrict__ dww,
                      const float* __restrict__ dwb, const float* __restrict__ pw,
                      float* __restrict__ vgrid) {
    int blk = blockIdx.x;          // bg*64 + hd*8 + wd
    int bg = blk >> 6;
    int hd = (blk >> 3) & 7;
    int wd = blk & 7;
    int ch = threadIdx.x;
    const float* qch = q + (size_t)(bg * 64 + ch) * HWP;
    float acc = 0.f;
#pragma unroll
    for (int kh = 0; kh < 6; kh++) {
        int hin = hd * 4 - 1 + kh;
        if (hin < 0 || hin >= HH) continue;
#pragma unroll
        for (int kw_ = 0; kw_ < 6; kw_++) {
            int win = wd * 4 - 1 + kw_;
            if (win < 0 || win >= WW) continue;
            acc = fmaf(qch[hin * WW + win], dww[ch * 36 + kh * 6 + kw_], acc);
        }
    }
    acc += dwb[ch];
    float ge = 0.5f * acc * (1.0f + erff(acc * 0.7071067811865475f));
    float p0 = ge * pw[ch];
    float p1 = ge * pw[64 + ch];
#pragma unroll
    for (int off = 32; off; off >>= 1) {
        p0 += __shfl_xor(p0, off);
        p1 += __shfl_xor(p1, off);
    }
    if (ch == 0) {
        float off0 = tanhf(p0) * 4.0f;
        float off1 = tanhf(p1) * 4.0f;
        float vx = (float)wd + off0;
        float vy = (float)hd + off1;
        float nx = 2.0f * vx / 7.0f - 1.0f;
        float ny = 2.0f * vy / 7.0f - 1.0f;
        vgrid[blk * 2] = nx;
        vgrid[blk * 2 + 1] = ny;
    }
}

// ---------------- K4: grid_sample ----------------
__global__ void k_sample(const float* __restrict__ xn, const float* __restrict__ vgrid,
                         float* __restrict__ kv) {
    int tid = blockIdx.x * 256 + threadIdx.x;   // 65536
    int bg = tid >> 12;
    int ch = (tid >> 6) & 63;
    int j = tid & 63;
    float nx = vgrid[(bg * 64 + j) * 2];
    float ny = vgrid[(bg * 64 + j) * 2 + 1];
    float gx = (nx + 1.0f) * 16.0f - 0.5f;
    float gy = (ny + 1.0f) * 16.0f - 0.5f;
    float x0f = floorf(gx), y0f = floorf(gy);
    float wx = gx - x0f, wy = gy - y0f;
    int x0 = (int)x0f, y0 = (int)y0f;
    const float* im = xn + (size_t)(bg * 64 + ch) * HWP;
    float v00 = (x0 >= 0 && x0 < WW && y0 >= 0 && y0 < HH) ? im[y0 * WW + x0] : 0.f;
    float v01 = (x0 + 1 >= 0 && x0 + 1 < WW && y0 >= 0 && y0 < HH) ? im[y0 * WW + x0 + 1] : 0.f;
    float v10 = (x0 >= 0 && x0 < WW && y0 + 1 >= 0 && y0 + 1 < HH) ? im[(y0 + 1) * WW + x0] : 0.f;
    float v11 = (x0 + 1 >= 0 && x0 + 1 < WW && y0 + 1 >= 0 && y0 + 1 < HH) ? im[(y0 + 1) * WW + x0 + 1] : 0.f;
    float val = v00 * (1 - wx) * (1 - wy) + v01 * wx * (1 - wy)
              + v10 * (1 - wx) * wy + v11 * wx * wy;
    kv[tid] = val;
}

// ---------------- K5: k/v grouped 1x1 convs ----------------
__global__ void k_kvconv(const float* __restrict__ kv, const float* __restrict__ kw,
                         const float* __restrict__ vw, float* __restrict__ kk,
                         float* __restrict__ vv) {
    int tid = blockIdx.x * 256 + threadIdx.x;   // 65536
    int bg = tid >> 12;
    int j = (tid >> 6) & 63;
    int o = tid & 63;
    int g = bg & 7;
    const float* kvp = kv + (size_t)bg * 4096 + j;   // [bg][c][j]
    const float* kwr = kw + (g * 64 + o) * 64;
    const float* vwr = vw + (g * 64 + o) * 64;
    float ak = 0.f, av = 0.f;
#pragma unroll
    for (int c = 0; c < 64; c++) {
        float t = kvp[c * 64];
        ak = fmaf(t, kwr[c], ak);
        av = fmaf(t, vwr[c], av);
    }
    kk[tid] = ak;
    vv[tid] = av;
}

// ---------------- K6: CPB bias MLP via bf16 MFMA ----------------
__global__ __launch_bounds__(256) void k_cpb(
    const float* __restrict__ vgrid,
    const float* __restrict__ w1, const float* __restrict__ b1,
    const float* __restrict__ w2, const float* __restrict__ b2,
    const float* __restrict__ w3, const float* __restrict__ b3,
    float* __restrict__ bias) {
    __shared__ __align__(16) short w2fs[16384];   // 32 KB: B-frags [nt*4+kc][lane][jj]
    int tid = threadIdx.x;
    for (int idx = tid; idx < 16384; idx += 256) {
        int k = idx >> 7, n = idx & 127;
        int dest = ((((n >> 4) * 4 + (k >> 5)) * 64) + (((k >> 3) & 3) * 16) + (n & 15)) * 8 + (k & 7);
        w2fs[dest] = f2bf(w2[idx]);
    }
    __syncthreads();

    int lane = tid & 63;
    int wv = tid >> 6;
    int l15 = lane & 15;
    int quad = lane >> 4;

    float cu[4][8], cv[4][8], cc[4][8];
#pragma unroll
    for (int kc = 0; kc < 4; kc++) {
        int kb = kc * 32 + quad * 8;
#pragma unroll
        for (int jj = 0; jj < 8; jj++) {
            cu[kc][jj] = w1[kb + jj];
            cv[kc][jj] = w1[128 + kb + jj];
            cc[kc][jj] = b1[kb + jj];
        }
    }
    float b2v[8], w3v[8];
#pragma unroll
    for (int nt = 0; nt < 8; nt++) {
        b2v[nt] = b2[nt * 16 + l15];
        w3v[nt] = w3[nt * 16 + l15];
    }
    float bias3 = b3[0];

    for (int it = 0; it < 4; it++) {
        int p = (blockIdx.x * 4 + it) * 4 + wv;       // pair index 0..32767
        int bg = p >> 11;
        int i = (p >> 1) & 1023;
        int jbase = (p & 1) * 32;
        int hi = i >> 5, wi = i & 31;
        float qx = 2.0f * (float)wi / 31.0f - 1.0f;
        float qy = 2.0f * (float)hi / 31.0f - 1.0f;

        int jA = jbase + l15;
        float gkxA = vgrid[(bg * 64 + jA) * 2];
        float gkyA = vgrid[(bg * 64 + jA) * 2 + 1];
        float gkxB = vgrid[(bg * 64 + jA + 16) * 2];
        float gkyB = vgrid[(bg * 64 + jA + 16) * 2 + 1];
        float p0 = qx - gkxA, p1 = qy - gkyA;
        float s0a = copysignf(log1pf(fabsf(p0)), p0);
        float s1a = copysignf(log1pf(fabsf(p1)), p1);
        p0 = qx - gkxB; p1 = qy - gkyB;
        float s0b = copysignf(log1pf(fabsf(p0)), p0);
        float s1b = copysignf(log1pf(fabsf(p1)), p1);

        f32x4 acc0[8], acc1[8];
#pragma unroll
        for (int nt = 0; nt < 8; nt++) {
            acc0[nt] = (f32x4){0.f, 0.f, 0.f, 0.f};
            acc1[nt] = (f32x4){0.f, 0.f, 0.f, 0.f};
        }

#pragma unroll
        for (int kc = 0; kc < 4; kc++) {
            short8 a0, a1;
#pragma unroll
            for (int jj = 0; jj < 8; jj++) {
                float h = fmaf(s0a, cu[kc][jj], fmaf(s1a, cv[kc][jj], cc[kc][jj]));
                a0[jj] = f2bf(fmaxf(h, 0.f));
                h = fmaf(s0b, cu[kc][jj], fmaf(s1b, cv[kc][jj], cc[kc][jj]));
                a1[jj] = f2bf(fmaxf(h, 0.f));
            }
#pragma unroll
            for (int nt = 0; nt < 8; nt++) {
                short8 bf = *(const short8*)(w2fs + (((nt * 4 + kc) * 64) + lane) * 8);
                acc0[nt] = __builtin_amdgcn_mfma_f32_16x16x32_bf16(a0, bf, acc0[nt], 0, 0, 0);
                acc1[nt] = __builtin_amdgcn_mfma_f32_16x16x32_bf16(a1, bf, acc1[nt], 0, 0, 0);
            }
        }

        int t0 = p * 2;
#pragma unroll
        for (int tt = 0; tt < 2; tt++) {
            float partial[4] = {0.f, 0.f, 0.f, 0.f};
#pragma unroll
            for (int nt = 0; nt < 8; nt++) {
                f32x4 a = tt ? acc1[nt] : acc0[nt];
#pragma unroll
                for (int r = 0; r < 4; r++) {
                    float h2 = a[r] + b2v[nt];
                    partial[r] = fmaf(fmaxf(h2, 0.f), w3v[nt], partial[r]);
                }
            }
#pragma unroll
            for (int m = 1; m <= 8; m <<= 1) {
#pragma unroll
                for (int r = 0; r < 4; r++) partial[r] += __shfl_xor(partial[r], m);
            }
            if (l15 == 0) {
                f32x4 outv = {partial[0] + bias3, partial[1] + bias3,
                              partial[2] + bias3, partial[3] + bias3};
                *(f32x4*)(bias + (t0 + tt) * 16 + quad * 4) = outv;
            }
        }
    }
}

// ---------------- K7: attention (bias precomputed) ----------------
__global__ __launch_bounds__(64) void k_attn(
    const float* __restrict__ q, const float* __restrict__ kk,
    const float* __restrict__ vv, const float* __restrict__ bias,
    float* __restrict__ ao) {
    __shared__ float ks[64 * 65];
    __shared__ float attn_s[64];
    int blk = blockIdx.x;
    int bg = blk >> 10;
    int i = blk & 1023;
    int b = bg >> 3, g = bg & 7;
    int j = threadIdx.x;

    for (int idx = j; idx < 4096; idx += 64)
        ks[(idx >> 6) * 65 + (idx & 63)] = kk[bg * 4096 + idx];
    __syncthreads();

    const float* qrow = q + (size_t)(b * CC + g * 64) * HWP + i;  // uniform
    float sim = 0.f;
#pragma unroll
    for (int d = 0; d < 64; d++) sim = fmaf(qrow[d * HWP], ks[j * 65 + d], sim);
    sim = sim * 0.125f + bias[(size_t)blk * 64 + j];

    float m = sim;
#pragma unroll
    for (int off = 32; off; off >>= 1) m = fmaxf(m, __shfl_xor(m, off));
    float p = expf(sim - m);
    float l = p;
#pragma unroll
    for (int off = 32; off; off >>= 1) l += __shfl_xor(l, off);
    attn_s[j] = p / l;
    __syncthreads();

    int d = j;
    float out = 0.f;
#pragma unroll
    for (int jj = 0; jj < 64; jj++)
        out = fmaf(attn_s[jj], vv[(size_t)(bg * 64 + jj) * 64 + d], out);
    ao[(size_t)(b * CC + g * 64 + d) * HWP + i] = out;
}

// ---------------- K8/K10/K11: tiled bf16-MFMA GEMM ----------------
// out[b][m][i] = epi( sum_k A[m][k] * B[b][k][i] + bias[m] )
// EPI 0: + resid, fp32 out.  EPI 1: gelu, bf16 out.  EPI 2: + resid, fp32 out.
// Block tile 64(M) x 64(N), BK=64; 4 waves, each 32x32. Grid = MT*32 blocks.
template<int EPI, int KD, int MT, bool BBF>
__global__ __launch_bounds__(256) void k_gemm(
    const float* __restrict__ A, const void* __restrict__ Bp,
    const float* __restrict__ resid, const float* __restrict__ bias,
    void* __restrict__ outp) {
    constexpr int MM = MT * 64;
    __shared__ __align__(16) short As[64][72];
    __shared__ __align__(16) short Bs[64][72];
    int tid = threadIdx.x;
    int blk = blockIdx.x;
    int mt = blk & (MT - 1);
    int nb = blk / MT;              // 0..31
    int bb = nb >> 4, nt = nb & 15;
    int m0 = mt * 64, i0 = nt * 64;
    int lane = tid & 63, wv = tid >> 6;
    int wm = (wv >> 1) * 32, wn = (wv & 1) * 32;
    int l15 = lane & 15, quad = lane >> 4;
    const float* Af = A + (size_t)m0 * KD;
    const float* Bf = (const float*)Bp;
    const unsigned short* Bh = (const unsigned short*)Bp;

    f32x4 acc[2][2];
#pragma unroll
    for (int a = 0; a < 2; a++)
#pragma unroll
        for (int c = 0; c < 2; c++) acc[a][c] = (f32x4){0.f, 0.f, 0.f, 0.f};

    for (int k0 = 0; k0 < KD; k0 += 64) {
        __syncthreads();
        // stage A: 64 rows x 64 k, float4 reads, packed b64 LDS writes
        {
            int kk4 = (tid & 15) * 4;
            int myb = tid >> 4;               // 0..15
#pragma unroll
            for (int p = 0; p < 4; p++) {
                int my = myb + p * 16;
                f32x4 v = *(const f32x4*)(Af + (size_t)my * KD + k0 + kk4);
                s16x4 s = {f2bf(v.x), f2bf(v.y), f2bf(v.z), f2bf(v.w)};
                *(s16x4*)&As[my][kk4] = s;
            }
        }
        // stage B transposed: Bs[n][k]
        {
            int i4 = (tid & 15) * 4;
            int kyb = tid >> 4;
#pragma unroll
            for (int p = 0; p < 4; p++) {
                int ky = kyb + p * 16;
                size_t goff = (size_t)bb * KD * HWP + (size_t)(k0 + ky) * HWP + i0 + i4;
                if (BBF) {
                    u16x4 v = *(const u16x4*)(Bh + goff);
                    Bs[i4 + 0][ky] = (short)v.x;
                    Bs[i4 + 1][ky] = (short)v.y;
                    Bs[i4 + 2][ky] = (short)v.z;
                    Bs[i4 + 3][ky] = (short)v.w;
                } else {
                    f32x4 v = *(const f32x4*)(Bf + goff);
                    Bs[i4 + 0][ky] = f2bf(v.x);
                    Bs[i4 + 1][ky] = f2bf(v.y);
                    Bs[i4 + 2][ky] = f2bf(v.z);
                    Bs[i4 + 3][ky] = f2bf(v.w);
                }
            }
        }
        __syncthreads();
#pragma unroll
        for (int ks = 0; ks < 2; ks++) {
            short8 af0 = *(const short8*)&As[wm + l15][ks * 32 + quad * 8];
            short8 af1 = *(const short8*)&As[wm + 16 + l15][ks * 32 + quad * 8];
            short8 bf0 = *(const short8*)&Bs[wn + l15][ks * 32 + quad * 8];
            short8 bf1 = *(const short8*)&Bs[wn + 16 + l15][ks * 32 + quad * 8];
            acc[0][0] = __builtin_amdgcn_mfma_f32_16x16x32_bf16(af0, bf0, acc[0][0], 0, 0, 0);
            acc[0][1] = __builtin_amdgcn_mfma_f32_16x16x32_bf16(af0, bf1, acc[0][1], 0, 0, 0);
            acc[1][0] = __builtin_amdgcn_mfma_f32_16x16x32_bf16(af1, bf0, acc[1][0], 0, 0, 0);
            acc[1][1] = __builtin_amdgcn_mfma_f32_16x16x32_bf16(af1, bf1, acc[1][1], 0, 0, 0);
        }
    }

    float* outF = (float*)outp;
    unsigned short* outH = (unsigned short*)outp;
#pragma unroll
    for (int im = 0; im < 2; im++) {
#pragma unroll
        for (int r = 0; r < 4; r++) {
            int m = m0 + wm + im * 16 + quad * 4 + r;
            float bv = bias[m];
#pragma unroll
            for (int in_ = 0; in_ < 2; in_++) {
                int n = i0 + wn + in_ * 16 + l15;
                size_t idx = ((size_t)bb * MM + m) * HWP + n;
                float v = acc[im][in_][r] + bv;
                if constexpr (EPI == 1) {
                    float ge = 0.5f * v * (1.0f + erff(v * 0.7071067811865475f));
                    outH[idx] = (unsigned short)f2bf(ge);
                } else {
                    outF[idx] = v + resid[idx];
                }
            }
        }
    }
}

// ---------------- K9: BN2 ----------------
__global__ void k_bn2(const float* __restrict__ xo, const float* __restrict__ g,
                      const float* __restrict__ b, float* __restrict__ xn2) {
    int idx = blockIdx.x * 256 + threadIdx.x;
    int c = (idx >> 10) & (CC - 1);
    float s = g[c] / sqrtf(1.0f + EPS);
    xn2[idx] = xo[idx] * s + b[c];
}

extern "C" void kernel_launch(void* const* d_in, const int* in_sizes, int n_in,
                              void* d_out, int out_size, void* d_ws, size_t ws_size,
                              hipStream_t stream) {
    const float* x      = (const float*)d_in[0];
    const float* bn1_g  = (const float*)d_in[1];
    const float* bn1_b  = (const float*)d_in[2];
    const float* bn2_g  = (const float*)d_in[3];
    const float* bn2_b  = (const float*)d_in[4];
    const float* qw     = (const float*)d_in[5];
    const float* kw     = (const float*)d_in[6];
    const float* vw     = (const float*)d_in[7];
    const float* out_w  = (const float*)d_in[8];
    const float* out_b  = (const float*)d_in[9];
    const float* off_dw_w = (const float*)d_in[10];
    const float* off_dw_b = (const float*)d_in[11];
    const float* off_pw_w = (const float*)d_in[12];
    const float* cpb_w1 = (const float*)d_in[13];
    const float* cpb_b1 = (const float*)d_in[14];
    const float* cpb_w2 = (const float*)d_in[15];
    const float* cpb_b2 = (const float*)d_in[16];
    const float* cpb_w3 = (const float*)d_in[17];
    const float* cpb_b3 = (const float*)d_in[18];
    const float* mlp_w1 = (const float*)d_in[19];
    const float* mlp_b1 = (const float*)d_in[20];
    const float* mlp_w2 = (const float*)d_in[21];
    const float* mlp_b2 = (const float*)d_in[22];

    float* ws = (float*)d_ws;
    // workspace layout (floats)
    float* xn    = ws + 0;            // 1,048,576 (reused as xn2)
    float* q     = ws + 1048576;      // 1,048,576
    float* vgrid = ws + 2097152;      // 2,048
    float* kv    = ws + 2099200;      // 65,536
    float* kk    = ws + 2164736;      // 65,536
    float* vv    = ws + 2230272;      // 65,536
    float* ao    = ws + 2312192;      // 1,048,576
    float* xo    = ws + 3360768;      // 1,048,576
    float* h1of  = ws + 4409344;      // region reused: bias (1M floats) then h1o bf16 (4M ushorts = 2M floats)
    float* biasb = h1of;              // 1,048,576 floats — consumed by k_attn before k_mlp1 writes h1o
    unsigned short* h1o = (unsigned short*)h1of;  // 4,194,304 bf16

    hipLaunchKernelGGL(k_bn1, dim3(4096), dim3(256), 0, stream, x, bn1_g, bn1_b, xn);
    hipLaunchKernelGGL(k_qconv, dim3(1024, 4), dim3(256), 0, stream, xn, qw, q);
    hipLaunchKernelGGL(k_off, dim3(1024), dim3(64), 0, stream, q, off_dw_w, off_dw_b, off_pw_w, vgrid);
    hipLaunchKernelGGL(k_sample, dim3(256), dim3(256), 0, stream, xn, vgrid, kv);
    hipLaunchKernelGGL(k_kvconv, dim3(256), dim3(256), 0, stream, kv, kw, vw, kk, vv);
    hipLaunchKernelGGL(k_cpb, dim3(2048), dim3(256), 0, stream,
                       vgrid, cpb_w1, cpb_b1, cpb_w2, cpb_b2, cpb_w3, cpb_b3, biasb);
    hipLaunchKernelGGL(k_attn, dim3(16384), dim3(64), 0, stream, q, kk, vv, biasb, ao);
    // out projection: M=512 (MT=8), K=512, B=ao fp32, resid=x -> xo
    k_gemm<0, 512, 8, false><<<dim3(256), dim3(256), 0, stream>>>(out_w, ao, x, out_b, xo);
    hipLaunchKernelGGL(k_bn2, dim3(4096), dim3(256), 0, stream, xo, bn2_g, bn2_b, xn);
    // MLP1: M=2048 (MT=32), K=512, B=xn fp32, gelu -> h1o (bf16)
    k_gemm<1, 512, 32, false><<<dim3(1024), dim3(256), 0, stream>>>(mlp_w1, xn, nullptr, mlp_b1, h1o);
    // MLP2: M=512 (MT=8), K=2048, B=h1o bf16, resid=xo -> d_out
    k_gemm<2, 2048, 8, true><<<dim3(256), dim3(256), 0, stream>>>(mlp_w2, h1o, xo, mlp_b2, d_out);
}

// Round 4
// 367.433 us; speedup vs baseline: 3.8626x; 1.0724x over previous
//
#include <hip/hip_runtime.h>
#include <hip/hip_bf16.h>
#include <math.h>

// Problem constants
#define BB 2
#define CC 512
#define HH 32
#define WW 32
#define HWP 1024      // H*W
#define GG 8
#define DH 64
#define HD 8
#define WD 8
#define JJ 64         // HD*WD
#define BG 16         // BB*GG
#define EPS 1e-5f

typedef __attribute__((ext_vector_type(8))) short short8;
typedef __attribute__((ext_vector_type(4))) short s16x4;
typedef __attribute__((ext_vector_type(4))) float f32x4;
typedef __attribute__((ext_vector_type(4))) unsigned short u16x4;
typedef __attribute__((ext_vector_type(4))) unsigned int u32x4;

// RNE float -> bf16 bits
static __device__ __forceinline__ short f2bf(float x) {
    unsigned u = __builtin_bit_cast(unsigned, x);
    u += 0x7FFFu + ((u >> 16) & 1u);
    return (short)(u >> 16);
}

// ---------------- K1: BN1 ----------------
__global__ void k_bn1(const float* __restrict__ x, const float* __restrict__ g,
                      const float* __restrict__ b, float* __restrict__ xn) {
    int idx = blockIdx.x * 256 + threadIdx.x;          // 1,048,576 total
    int c = (idx >> 10) & (CC - 1);
    float s = g[c] / sqrtf(1.0f + EPS);
    xn[idx] = x[idx] * s + b[c];
}

// ---------------- K2: q grouped 1x1 conv ----------------
__global__ void k_qconv(const float* __restrict__ xn, const float* __restrict__ qw,
                        float* __restrict__ q) {
    int o_lin = blockIdx.x;                  // b*512 + g*64 + o
    int i = blockIdx.y * 256 + threadIdx.x;
    int b = o_lin >> 9;
    int g = (o_lin >> 6) & 7;
    int o = o_lin & 63;
    const float* wrow = qw + (g * 64 + o) * 64;
    const float* xin = xn + (size_t)(b * CC + g * 64) * HWP + i;
    float acc = 0.f;
#pragma unroll
    for (int c = 0; c < 64; c++) acc = fmaf(xin[c * HWP], wrow[c], acc);
    q[(size_t)o_lin * HWP + i] = acc;
}

// ---------------- K3: offsets -> vgrid ----------------
__global__ void k_off(const float* __restrict__ q, const float* __restrict__ dww,
                      const float* __restrict__ dwb, const float* __restrict__ pw,
                      float* __restrict__ vgrid) {
    int blk = blockIdx.x;          // bg*64 + hd*8 + wd
    int bg = blk >> 6;
    int hd = (blk >> 3) & 7;
    int wd = blk & 7;
    int ch = threadIdx.x;
    const float* qch = q + (size_t)(bg * 64 + ch) * HWP;
    float acc = 0.f;
#pragma unroll
    for (int kh = 0; kh < 6; kh++) {
        int hin = hd * 4 - 1 + kh;
        if (hin < 0 || hin >= HH) continue;
#pragma unroll
        for (int kw_ = 0; kw_ < 6; kw_++) {
            int win = wd * 4 - 1 + kw_;
            if (win < 0 || win >= WW) continue;
            acc = fmaf(qch[hin * WW + win], dww[ch * 36 + kh * 6 + kw_], acc);
        }
    }
    acc += dwb[ch];
    float ge = 0.5f * acc * (1.0f + erff(acc * 0.7071067811865475f));
    float p0 = ge * pw[ch];
    float p1 = ge * pw[64 + ch];
#pragma unroll
    for (int off = 32; off; off >>= 1) {
        p0 += __shfl_xor(p0, off);
        p1 += __shfl_xor(p1, off);
    }
    if (ch == 0) {
        float off0 = tanhf(p0) * 4.0f;
        float off1 = tanhf(p1) * 4.0f;
        float vx = (float)wd + off0;
        float vy = (float)hd + off1;
        float nx = 2.0f * vx / 7.0f - 1.0f;
        float ny = 2.0f * vy / 7.0f - 1.0f;
        vgrid[blk * 2] = nx;
        vgrid[blk * 2 + 1] = ny;
    }
}

// ---------------- K4: grid_sample ----------------
__global__ void k_sample(const float* __restrict__ xn, const float* __restrict__ vgrid,
                         float* __restrict__ kv) {
    int tid = blockIdx.x * 256 + threadIdx.x;   // 65536
    int bg = tid >> 12;
    int ch = (tid >> 6) & 63;
    int j = tid & 63;
    float nx = vgrid[(bg * 64 + j) * 2];
    float ny = vgrid[(bg * 64 + j) * 2 + 1];
    float gx = (nx + 1.0f) * 16.0f - 0.5f;
    float gy = (ny + 1.0f) * 16.0f - 0.5f;
    float x0f = floorf(gx), y0f = floorf(gy);
    float wx = gx - x0f, wy = gy - y0f;
    int x0 = (int)x0f, y0 = (int)y0f;
    const float* im = xn + (size_t)(bg * 64 + ch) * HWP;
    float v00 = (x0 >= 0 && x0 < WW && y0 >= 0 && y0 < HH) ? im[y0 * WW + x0] : 0.f;
    float v01 = (x0 + 1 >= 0 && x0 + 1 < WW && y0 >= 0 && y0 < HH) ? im[y0 * WW + x0 + 1] : 0.f;
    float v10 = (x0 >= 0 && x0 < WW && y0 + 1 >= 0 && y0 + 1 < HH) ? im[(y0 + 1) * WW + x0] : 0.f;
    float v11 = (x0 + 1 >= 0 && x0 + 1 < WW && y0 + 1 >= 0 && y0 + 1 < HH) ? im[(y0 + 1) * WW + x0 + 1] : 0.f;
    float val = v00 * (1 - wx) * (1 - wy) + v01 * wx * (1 - wy)
              + v10 * (1 - wx) * wy + v11 * wx * wy;
    kv[tid] = val;
}

// ---------------- K5: k/v grouped 1x1 convs ----------------
__global__ void k_kvconv(const float* __restrict__ kv, const float* __restrict__ kw,
                         const float* __restrict__ vw, float* __restrict__ kk,
                         float* __restrict__ vv) {
    int tid = blockIdx.x * 256 + threadIdx.x;   // 65536
    int bg = tid >> 12;
    int j = (tid >> 6) & 63;
    int o = tid & 63;
    int g = bg & 7;
    const float* kvp = kv + (size_t)bg * 4096 + j;   // [bg][c][j]
    const float* kwr = kw + (g * 64 + o) * 64;
    const float* vwr = vw + (g * 64 + o) * 64;
    float ak = 0.f, av = 0.f;
#pragma unroll
    for (int c = 0; c < 64; c++) {
        float t = kvp[c * 64];
        ak = fmaf(t, kwr[c], ak);
        av = fmaf(t, vwr[c], av);
    }
    kk[tid] = ak;
    vv[tid] = av;
}

// ---------------- K5b: pre-pack W2 into bf16 fragment order (global) ----------------
// frag layout: [frag = (n>>4)*4 + (k>>5)][lane = ((k>>3)&3)*16 + (n&15)][j = k&7]
__global__ void k_w2pack(const float* __restrict__ w2, unsigned short* __restrict__ w2p) {
    int idx = blockIdx.x * 256 + threadIdx.x;   // 16384
    int k = idx >> 7, n = idx & 127;
    int dest = ((((n >> 4) * 4 + (k >> 5)) * 64) + (((k >> 3) & 3) * 16) + (n & 15)) * 8 + (k & 7);
    w2p[dest] = (unsigned short)f2bf(w2[idx]);
}

// ---------------- K6: CPB bias MLP via bf16 MFMA (v2) ----------------
// Orientation: A = W2-frag (rows = n_out), B = h1 (cols = batch rows).
// D col = l15 = batch row, D row = quad*4+r = n_out slice -> epilogue is
// in-lane over n_out (8 nt x 4 r) + 2 shuffles over quad. Coefficients live
// in LDS (broadcast reads) to keep VGPRs low.
__global__ __launch_bounds__(256) void k_cpb(
    const float* __restrict__ vgrid, const unsigned short* __restrict__ w2p,
    const float* __restrict__ w1, const float* __restrict__ b1,
    const float* __restrict__ b2, const float* __restrict__ w3,
    const float* __restrict__ b3, float* __restrict__ bias) {
    __shared__ __align__(16) short w2fs[16384];   // 32 KB frag-ordered bf16
    __shared__ __align__(16) float coef[640];     // w1(256) b1(128) b2(128) w3(128)
    int tid = threadIdx.x;
    // straight coalesced 16B-chunk copy of pre-packed W2
    {
        const u32x4* src = (const u32x4*)w2p;
        u32x4* dst = (u32x4*)w2fs;
        for (int c = tid; c < 2048; c += 256) dst[c] = src[c];
    }
    if (tid < 256) coef[tid] = w1[tid];
    else if (tid < 384) coef[tid] = b1[tid - 256];
    else if (tid < 512) coef[tid] = b2[tid - 384];
    if (tid >= 128 && tid < 256) coef[512 + tid - 128] = w3[tid - 128];
    float bias3 = b3[0];
    __syncthreads();

    int lane = tid & 63;
    int wv = tid >> 6;
    int l15 = lane & 15;
    int quad = lane >> 4;

    for (int it = 0; it < 4; it++) {
        int p = (blockIdx.x * 4 + it) * 4 + wv;       // pair index 0..32767
        int bg = p >> 11;
        int i = (p >> 1) & 1023;
        int jbase = (p & 1) * 32;
        int hi = i >> 5, wi = i & 31;
        float qx = 2.0f * (float)wi / 31.0f - 1.0f;
        float qy = 2.0f * (float)hi / 31.0f - 1.0f;

        int jA = jbase + l15;
        float gkxA = vgrid[(bg * 64 + jA) * 2];
        float gkyA = vgrid[(bg * 64 + jA) * 2 + 1];
        float gkxB = vgrid[(bg * 64 + jA + 16) * 2];
        float gkyB = vgrid[(bg * 64 + jA + 16) * 2 + 1];
        float p0 = qx - gkxA, p1 = qy - gkyA;
        float s0a = copysignf(log1pf(fabsf(p0)), p0);
        float s1a = copysignf(log1pf(fabsf(p1)), p1);
        p0 = qx - gkxB; p1 = qy - gkyB;
        float s0b = copysignf(log1pf(fabsf(p0)), p0);
        float s1b = copysignf(log1pf(fabsf(p1)), p1);

        f32x4 acc0[8], acc1[8];
#pragma unroll
        for (int nt = 0; nt < 8; nt++) {
            acc0[nt] = (f32x4){0.f, 0.f, 0.f, 0.f};
            acc1[nt] = (f32x4){0.f, 0.f, 0.f, 0.f};
        }

#pragma unroll
        for (int kc = 0; kc < 4; kc++) {
            // quad-uniform broadcast reads of layer-1 coefficients
            f32x4 cu0 = *(const f32x4*)&coef[kc * 32 + quad * 8];
            f32x4 cu1 = *(const f32x4*)&coef[kc * 32 + quad * 8 + 4];
            f32x4 cv0 = *(const f32x4*)&coef[128 + kc * 32 + quad * 8];
            f32x4 cv1 = *(const f32x4*)&coef[128 + kc * 32 + quad * 8 + 4];
            f32x4 cb0 = *(const f32x4*)&coef[256 + kc * 32 + quad * 8];
            f32x4 cb1 = *(const f32x4*)&coef[256 + kc * 32 + quad * 8 + 4];
            short8 h0, h1v;
#pragma unroll
            for (int jj = 0; jj < 4; jj++) {
                float u = cu0[jj], v = cv0[jj], c = cb0[jj];
                h0[jj]  = f2bf(fmaxf(fmaf(s0a, u, fmaf(s1a, v, c)), 0.f));
                h1v[jj] = f2bf(fmaxf(fmaf(s0b, u, fmaf(s1b, v, c)), 0.f));
                u = cu1[jj]; v = cv1[jj]; c = cb1[jj];
                h0[jj + 4]  = f2bf(fmaxf(fmaf(s0a, u, fmaf(s1a, v, c)), 0.f));
                h1v[jj + 4] = f2bf(fmaxf(fmaf(s0b, u, fmaf(s1b, v, c)), 0.f));
            }
#pragma unroll
            for (int nt = 0; nt < 8; nt++) {
                short8 af = *(const short8*)(w2fs + (((nt * 4 + kc) * 64) + lane) * 8);
                acc0[nt] = __builtin_amdgcn_mfma_f32_16x16x32_bf16(af, h0, acc0[nt], 0, 0, 0);
                acc1[nt] = __builtin_amdgcn_mfma_f32_16x16x32_bf16(af, h1v, acc1[nt], 0, 0, 0);
            }
        }

        // epilogue: in-lane over n_out (nt, r), then 2 shuffles over quad
#pragma unroll
        for (int tt = 0; tt < 2; tt++) {
            float psum = 0.f;
#pragma unroll
            for (int nt = 0; nt < 8; nt++) {
                f32x4 a = tt ? acc1[nt] : acc0[nt];
                f32x4 b2q = *(const f32x4*)&coef[384 + nt * 16 + quad * 4];
                f32x4 w3q = *(const f32x4*)&coef[512 + nt * 16 + quad * 4];
#pragma unroll
                for (int r = 0; r < 4; r++)
                    psum = fmaf(fmaxf(a[r] + b2q[r], 0.f), w3q[r], psum);
            }
            psum += __shfl_xor(psum, 16);
            psum += __shfl_xor(psum, 32);
            if (quad == 0) bias[(size_t)(p * 2 + tt) * 16 + l15] = psum + bias3;
        }
    }
}

// ---------------- K7: attention (bias precomputed) ----------------
__global__ __launch_bounds__(64) void k_attn(
    const float* __restrict__ q, const float* __restrict__ kk,
    const float* __restrict__ vv, const float* __restrict__ bias,
    float* __restrict__ ao) {
    __shared__ float ks[64 * 65];
    __shared__ float attn_s[64];
    int blk = blockIdx.x;
    int bg = blk >> 10;
    int i = blk & 1023;
    int b = bg >> 3, g = bg & 7;
    int j = threadIdx.x;

    for (int idx = j; idx < 4096; idx += 64)
        ks[(idx >> 6) * 65 + (idx & 63)] = kk[bg * 4096 + idx];
    __syncthreads();

    const float* qrow = q + (size_t)(b * CC + g * 64) * HWP + i;  // uniform
    float sim = 0.f;
#pragma unroll
    for (int d = 0; d < 64; d++) sim = fmaf(qrow[d * HWP], ks[j * 65 + d], sim);
    sim = sim * 0.125f + bias[(size_t)blk * 64 + j];

    float m = sim;
#pragma unroll
    for (int off = 32; off; off >>= 1) m = fmaxf(m, __shfl_xor(m, off));
    float p = expf(sim - m);
    float l = p;
#pragma unroll
    for (int off = 32; off; off >>= 1) l += __shfl_xor(l, off);
    attn_s[j] = p / l;
    __syncthreads();

    int d = j;
    float out = 0.f;
#pragma unroll
    for (int jj = 0; jj < 64; jj++)
        out = fmaf(attn_s[jj], vv[(size_t)(bg * 64 + jj) * 64 + d], out);
    ao[(size_t)(b * CC + g * 64 + d) * HWP + i] = out;
}

// ---------------- K8/K10/K11: tiled bf16-MFMA GEMM ----------------
// out[b][m][i] = epi( sum_k A[m][k] * B[b][k][i] + bias[m] )
// EPI 0: + resid, fp32 out.  EPI 1: gelu, bf16 out.  EPI 2: + resid, fp32 out.
template<int EPI, int KD, int MT, bool BBF>
__global__ __launch_bounds__(256) void k_gemm(
    const float* __restrict__ A, const void* __restrict__ Bp,
    const float* __restrict__ resid, const float* __restrict__ bias,
    void* __restrict__ outp) {
    constexpr int MM = MT * 64;
    __shared__ __align__(16) short As[64][72];
    __shared__ __align__(16) short Bs[64][72];
    int tid = threadIdx.x;
    int blk = blockIdx.x;
    int mt = blk & (MT - 1);
    int nb = blk / MT;              // 0..31
    int bb = nb >> 4, nt = nb & 15;
    int m0 = mt * 64, i0 = nt * 64;
    int lane = tid & 63, wv = tid >> 6;
    int wm = (wv >> 1) * 32, wn = (wv & 1) * 32;
    int l15 = lane & 15, quad = lane >> 4;
    const float* Af = A + (size_t)m0 * KD;
    const float* Bf = (const float*)Bp;
    const unsigned short* Bh = (const unsigned short*)Bp;

    f32x4 acc[2][2];
#pragma unroll
    for (int a = 0; a < 2; a++)
#pragma unroll
        for (int c = 0; c < 2; c++) acc[a][c] = (f32x4){0.f, 0.f, 0.f, 0.f};

    for (int k0 = 0; k0 < KD; k0 += 64) {
        __syncthreads();
        {
            int kk4 = (tid & 15) * 4;
            int myb = tid >> 4;               // 0..15
#pragma unroll
            for (int p = 0; p < 4; p++) {
                int my = myb + p * 16;
                f32x4 v = *(const f32x4*)(Af + (size_t)my * KD + k0 + kk4);
                s16x4 s = {f2bf(v.x), f2bf(v.y), f2bf(v.z), f2bf(v.w)};
                *(s16x4*)&As[my][kk4] = s;
            }
        }
        {
            int i4 = (tid & 15) * 4;
            int kyb = tid >> 4;
#pragma unroll
            for (int p = 0; p < 4; p++) {
                int ky = kyb + p * 16;
                size_t goff = (size_t)bb * KD * HWP + (size_t)(k0 + ky) * HWP + i0 + i4;
                if (BBF) {
                    u16x4 v = *(const u16x4*)(Bh + goff);
                    Bs[i4 + 0][ky] = (short)v.x;
                    Bs[i4 + 1][ky] = (short)v.y;
                    Bs[i4 + 2][ky] = (short)v.z;
                    Bs[i4 + 3][ky] = (short)v.w;
                } else {
                    f32x4 v = *(const f32x4*)(Bf + goff);
                    Bs[i4 + 0][ky] = f2bf(v.x);
                    Bs[i4 + 1][ky] = f2bf(v.y);
                    Bs[i4 + 2][ky] = f2bf(v.z);
                    Bs[i4 + 3][ky] = f2bf(v.w);
                }
            }
        }
        __syncthreads();
#pragma unroll
        for (int ks = 0; ks < 2; ks++) {
            short8 af0 = *(const short8*)&As[wm + l15][ks * 32 + quad * 8];
            short8 af1 = *(const short8*)&As[wm + 16 + l15][ks * 32 + quad * 8];
            short8 bf0 = *(const short8*)&Bs[wn + l15][ks * 32 + quad * 8];
            short8 bf1 = *(const short8*)&Bs[wn + 16 + l15][ks * 32 + quad * 8];
            acc[0][0] = __builtin_amdgcn_mfma_f32_16x16x32_bf16(af0, bf0, acc[0][0], 0, 0, 0);
            acc[0][1] = __builtin_amdgcn_mfma_f32_16x16x32_bf16(af0, bf1, acc[0][1], 0, 0, 0);
            acc[1][0] = __builtin_amdgcn_mfma_f32_16x16x32_bf16(af1, bf0, acc[1][0], 0, 0, 0);
            acc[1][1] = __builtin_amdgcn_mfma_f32_16x16x32_bf16(af1, bf1, acc[1][1], 0, 0, 0);
        }
    }

    float* outF = (float*)outp;
    unsigned short* outH = (unsigned short*)outp;
#pragma unroll
    for (int im = 0; im < 2; im++) {
#pragma unroll
        for (int r = 0; r < 4; r++) {
            int m = m0 + wm + im * 16 + quad * 4 + r;
            float bv = bias[m];
#pragma unroll
            for (int in_ = 0; in_ < 2; in_++) {
                int n = i0 + wn + in_ * 16 + l15;
                size_t idx = ((size_t)bb * MM + m) * HWP + n;
                float v = acc[im][in_][r] + bv;
                if constexpr (EPI == 1) {
                    float ge = 0.5f * v * (1.0f + erff(v * 0.7071067811865475f));
                    outH[idx] = (unsigned short)f2bf(ge);
                } else {
                    outF[idx] = v + resid[idx];
                }
            }
        }
    }
}

// ---------------- K9: BN2 ----------------
__global__ void k_bn2(const float* __restrict__ xo, const float* __restrict__ g,
                      const float* __restrict__ b, float* __restrict__ xn2) {
    int idx = blockIdx.x * 256 + threadIdx.x;
    int c = (idx >> 10) & (CC - 1);
    float s = g[c] / sqrtf(1.0f + EPS);
    xn2[idx] = xo[idx] * s + b[c];
}

extern "C" void kernel_launch(void* const* d_in, const int* in_sizes, int n_in,
                              void* d_out, int out_size, void* d_ws, size_t ws_size,
                              hipStream_t stream) {
    const float* x      = (const float*)d_in[0];
    const float* bn1_g  = (const float*)d_in[1];
    const float* bn1_b  = (const float*)d_in[2];
    const float* bn2_g  = (const float*)d_in[3];
    const float* bn2_b  = (const float*)d_in[4];
    const float* qw     = (const float*)d_in[5];
    const float* kw     = (const float*)d_in[6];
    const float* vw     = (const float*)d_in[7];
    const float* out_w  = (const float*)d_in[8];
    const float* out_b  = (const float*)d_in[9];
    const float* off_dw_w = (const float*)d_in[10];
    const float* off_dw_b = (const float*)d_in[11];
    const float* off_pw_w = (const float*)d_in[12];
    const float* cpb_w1 = (const float*)d_in[13];
    const float* cpb_b1 = (const float*)d_in[14];
    const float* cpb_w2 = (const float*)d_in[15];
    const float* cpb_b2 = (const float*)d_in[16];
    const float* cpb_w3 = (const float*)d_in[17];
    const float* cpb_b3 = (const float*)d_in[18];
    const float* mlp_w1 = (const float*)d_in[19];
    const float* mlp_b1 = (const float*)d_in[20];
    const float* mlp_w2 = (const float*)d_in[21];
    const float* mlp_b2 = (const float*)d_in[22];

    float* ws = (float*)d_ws;
    // workspace layout (floats)
    float* xn    = ws + 0;            // 1,048,576 (reused as xn2)
    float* q     = ws + 1048576;      // 1,048,576
    float* vgrid = ws + 2097152;      // 2,048
    float* kv    = ws + 2099200;      // 65,536
    float* kk    = ws + 2164736;      // 65,536
    float* vv    = ws + 2230272;      // 65,536
    unsigned short* w2p = (unsigned short*)(ws + 2295808);  // 16,384 bf16 (8,192 floats)
    float* ao    = ws + 2312192;      // 1,048,576
    float* xo    = ws + 3360768;      // 1,048,576
    float* h1of  = ws + 4409344;      // region reused: bias (1M floats) then h1o bf16
    float* biasb = h1of;              // 1,048,576 floats — consumed by k_attn before k_mlp1 writes h1o
    unsigned short* h1o = (unsigned short*)h1of;  // 4,194,304 bf16

    hipLaunchKernelGGL(k_bn1, dim3(4096), dim3(256), 0, stream, x, bn1_g, bn1_b, xn);
    hipLaunchKernelGGL(k_qconv, dim3(1024, 4), dim3(256), 0, stream, xn, qw, q);
    hipLaunchKernelGGL(k_off, dim3(1024), dim3(64), 0, stream, q, off_dw_w, off_dw_b, off_pw_w, vgrid);
    hipLaunchKernelGGL(k_sample, dim3(256), dim3(256), 0, stream, xn, vgrid, kv);
    hipLaunchKernelGGL(k_kvconv, dim3(256), dim3(256), 0, stream, kv, kw, vw, kk, vv);
    hipLaunchKernelGGL(k_w2pack, dim3(64), dim3(256), 0, stream, cpb_w2, w2p);
    hipLaunchKernelGGL(k_cpb, dim3(2048), dim3(256), 0, stream,
                       vgrid, w2p, cpb_w1, cpb_b1, cpb_b2, cpb_w3, cpb_b3, biasb);
    hipLaunchKernelGGL(k_attn, dim3(16384), dim3(64), 0, stream, q, kk, vv, biasb, ao);
    // out projection: M=512 (MT=8), K=512, B=ao fp32, resid=x -> xo
    k_gemm<0, 512, 8, false><<<dim3(256), dim3(256), 0, stream>>>(out_w, ao, x, out_b, xo);
    hipLaunchKernelGGL(k_bn2, dim3(4096), dim3(256), 0, stream, xo, bn2_g, bn2_b, xn);
    // MLP1: M=2048 (MT=32), K=512, B=xn fp32, gelu -> h1o (bf16)
    k_gemm<1, 512, 32, false><<<dim3(1024), dim3(256), 0, stream>>>(mlp_w1, xn, nullptr, mlp_b1, h1o);
    // MLP2: M=512 (MT=8), K=2048, B=h1o bf16, resid=xo -> d_out
    k_gemm<2, 2048, 8, true><<<dim3(256), dim3(256), 0, stream>>>(mlp_w2, h1o, xo, mlp_b2, d_out);
}

// Round 5
// 348.627 us; speedup vs baseline: 4.0710x; 1.0539x over previous
//
#include <hip/hip_runtime.h>
#include <hip/hip_bf16.h>
#include <math.h>

// Problem constants
#define BB 2
#define CC 512
#define HH 32
#define WW 32
#define HWP 1024      // H*W
#define GG 8
#define DH 64
#define HD 8
#define WD 8
#define JJ 64         // HD*WD
#define BG 16         // BB*GG
#define EPS 1e-5f

typedef __attribute__((ext_vector_type(8))) short short8;
typedef __attribute__((ext_vector_type(4))) short s16x4;
typedef __attribute__((ext_vector_type(4))) float f32x4;
typedef __attribute__((ext_vector_type(4))) unsigned short u16x4;
typedef __attribute__((ext_vector_type(4))) unsigned int u32x4;

// RNE float -> bf16 bits
static __device__ __forceinline__ short f2bf(float x) {
    unsigned u = __builtin_bit_cast(unsigned, x);
    u += 0x7FFFu + ((u >> 16) & 1u);
    return (short)(u >> 16);
}

// ---------------- K1: BN1 ----------------
__global__ void k_bn1(const float* __restrict__ x, const float* __restrict__ g,
                      const float* __restrict__ b, float* __restrict__ xn) {
    int idx = blockIdx.x * 256 + threadIdx.x;          // 1,048,576 total
    int c = (idx >> 10) & (CC - 1);
    float s = g[c] / sqrtf(1.0f + EPS);
    xn[idx] = x[idx] * s + b[c];
}

// ---------------- K2: q grouped 1x1 conv ----------------
__global__ void k_qconv(const float* __restrict__ xn, const float* __restrict__ qw,
                        float* __restrict__ q) {
    int o_lin = blockIdx.x;                  // b*512 + g*64 + o
    int i = blockIdx.y * 256 + threadIdx.x;
    int b = o_lin >> 9;
    int g = (o_lin >> 6) & 7;
    int o = o_lin & 63;
    const float* wrow = qw + (g * 64 + o) * 64;
    const float* xin = xn + (size_t)(b * CC + g * 64) * HWP + i;
    float acc = 0.f;
#pragma unroll
    for (int c = 0; c < 64; c++) acc = fmaf(xin[c * HWP], wrow[c], acc);
    q[(size_t)o_lin * HWP + i] = acc;
}

// ---------------- K3: offsets -> vgrid ----------------
__global__ void k_off(const float* __restrict__ q, const float* __restrict__ dww,
                      const float* __restrict__ dwb, const float* __restrict__ pw,
                      float* __restrict__ vgrid) {
    int blk = blockIdx.x;          // bg*64 + hd*8 + wd
    int bg = blk >> 6;
    int hd = (blk >> 3) & 7;
    int wd = blk & 7;
    int ch = threadIdx.x;
    const float* qch = q + (size_t)(bg * 64 + ch) * HWP;
    float acc = 0.f;
#pragma unroll
    for (int kh = 0; kh < 6; kh++) {
        int hin = hd * 4 - 1 + kh;
        if (hin < 0 || hin >= HH) continue;
#pragma unroll
        for (int kw_ = 0; kw_ < 6; kw_++) {
            int win = wd * 4 - 1 + kw_;
            if (win < 0 || win >= WW) continue;
            acc = fmaf(qch[hin * WW + win], dww[ch * 36 + kh * 6 + kw_], acc);
        }
    }
    acc += dwb[ch];
    float ge = 0.5f * acc * (1.0f + erff(acc * 0.7071067811865475f));
    float p0 = ge * pw[ch];
    float p1 = ge * pw[64 + ch];
#pragma unroll
    for (int off = 32; off; off >>= 1) {
        p0 += __shfl_xor(p0, off);
        p1 += __shfl_xor(p1, off);
    }
    if (ch == 0) {
        float off0 = tanhf(p0) * 4.0f;
        float off1 = tanhf(p1) * 4.0f;
        float vx = (float)wd + off0;
        float vy = (float)hd + off1;
        float nx = 2.0f * vx / 7.0f - 1.0f;
        float ny = 2.0f * vy / 7.0f - 1.0f;
        vgrid[blk * 2] = nx;
        vgrid[blk * 2 + 1] = ny;
    }
}

// ---------------- K4: grid_sample ----------------
__global__ void k_sample(const float* __restrict__ xn, const float* __restrict__ vgrid,
                         float* __restrict__ kv) {
    int tid = blockIdx.x * 256 + threadIdx.x;   // 65536
    int bg = tid >> 12;
    int ch = (tid >> 6) & 63;
    int j = tid & 63;
    float nx = vgrid[(bg * 64 + j) * 2];
    float ny = vgrid[(bg * 64 + j) * 2 + 1];
    float gx = (nx + 1.0f) * 16.0f - 0.5f;
    float gy = (ny + 1.0f) * 16.0f - 0.5f;
    float x0f = floorf(gx), y0f = floorf(gy);
    float wx = gx - x0f, wy = gy - y0f;
    int x0 = (int)x0f, y0 = (int)y0f;
    const float* im = xn + (size_t)(bg * 64 + ch) * HWP;
    float v00 = (x0 >= 0 && x0 < WW && y0 >= 0 && y0 < HH) ? im[y0 * WW + x0] : 0.f;
    float v01 = (x0 + 1 >= 0 && x0 + 1 < WW && y0 >= 0 && y0 < HH) ? im[y0 * WW + x0 + 1] : 0.f;
    float v10 = (x0 >= 0 && x0 < WW && y0 + 1 >= 0 && y0 + 1 < HH) ? im[(y0 + 1) * WW + x0] : 0.f;
    float v11 = (x0 + 1 >= 0 && x0 + 1 < WW && y0 + 1 >= 0 && y0 + 1 < HH) ? im[(y0 + 1) * WW + x0 + 1] : 0.f;
    float val = v00 * (1 - wx) * (1 - wy) + v01 * wx * (1 - wy)
              + v10 * (1 - wx) * wy + v11 * wx * wy;
    kv[tid] = val;
}

// ---------------- K5: k/v grouped 1x1 convs ----------------
__global__ void k_kvconv(const float* __restrict__ kv, const float* __restrict__ kw,
                         const float* __restrict__ vw, float* __restrict__ kk,
                         float* __restrict__ vv) {
    int tid = blockIdx.x * 256 + threadIdx.x;   // 65536
    int bg = tid >> 12;
    int j = (tid >> 6) & 63;
    int o = tid & 63;
    int g = bg & 7;
    const float* kvp = kv + (size_t)bg * 4096 + j;   // [bg][c][j]
    const float* kwr = kw + (g * 64 + o) * 64;
    const float* vwr = vw + (g * 64 + o) * 64;
    float ak = 0.f, av = 0.f;
#pragma unroll
    for (int c = 0; c < 64; c++) {
        float t = kvp[c * 64];
        ak = fmaf(t, kwr[c], ak);
        av = fmaf(t, vwr[c], av);
    }
    kk[tid] = ak;
    vv[tid] = av;
}

// ---------------- K5b: pre-pack W2 into bf16 fragment order (global) ----------------
// frag layout: [frag = (n>>4)*4 + (k>>5)][lane = ((k>>3)&3)*16 + (n&15)][j = k&7]
__global__ void k_w2pack(const float* __restrict__ w2, unsigned short* __restrict__ w2p) {
    int idx = blockIdx.x * 256 + threadIdx.x;   // 16384
    int k = idx >> 7, n = idx & 127;
    int dest = ((((n >> 4) * 4 + (k >> 5)) * 64) + (((k >> 3) & 3) * 16) + (n & 15)) * 8 + (k & 7);
    w2p[dest] = (unsigned short)f2bf(w2[idx]);
}

// ---------------- K6: CPB bias MLP via bf16 MFMA (v3) ----------------
// A = W2-frag (rows = n_out), B = h1 (cols = batch rows). nt-outer rolled loop
// keeps only 2 accumulators + 1 fragment live -> low VGPR, high occupancy.
// h1 computed once per pair into 8 short8 regs, packed 2-at-a-time via v_perm.
__global__ __launch_bounds__(256) void k_cpb(
    const float* __restrict__ vgrid, const unsigned short* __restrict__ w2p,
    const float* __restrict__ w1, const float* __restrict__ b1,
    const float* __restrict__ b2, const float* __restrict__ w3,
    const float* __restrict__ b3, float* __restrict__ bias) {
    __shared__ __align__(16) short w2fs[16384];   // 32 KB frag-ordered bf16
    __shared__ __align__(16) float coef[640];     // w1(256) b1(128) b2(128) w3(128)
    int tid = threadIdx.x;
    {
        const u32x4* src = (const u32x4*)w2p;
        u32x4* dst = (u32x4*)w2fs;
        for (int c = tid; c < 2048; c += 256) dst[c] = src[c];
    }
    if (tid < 256) coef[tid] = w1[tid];
    else if (tid < 384) coef[tid] = b1[tid - 256];
    else if (tid < 512) coef[tid] = b2[tid - 384];
    if (tid >= 128 && tid < 256) coef[512 + tid - 128] = w3[tid - 128];
    float bias3 = b3[0];
    __syncthreads();

    int lane = tid & 63;
    int wv = tid >> 6;
    int l15 = lane & 15;
    int quad = lane >> 4;

#pragma unroll 1
    for (int it = 0; it < 4; it++) {
        int p = (blockIdx.x * 4 + it) * 4 + wv;       // pair index 0..32767
        int bg = p >> 11;
        int i = (p >> 1) & 1023;
        int jbase = (p & 1) * 32;
        int hi = i >> 5, wi = i & 31;
        float qx = 2.0f * (float)wi / 31.0f - 1.0f;
        float qy = 2.0f * (float)hi / 31.0f - 1.0f;

        int jA = jbase + l15;
        float gkxA = vgrid[(bg * 64 + jA) * 2];
        float gkyA = vgrid[(bg * 64 + jA) * 2 + 1];
        float gkxB = vgrid[(bg * 64 + jA + 16) * 2];
        float gkyB = vgrid[(bg * 64 + jA + 16) * 2 + 1];
        float p0 = qx - gkxA, p1 = qy - gkyA;
        float s0a = copysignf(log1pf(fabsf(p0)), p0);
        float s1a = copysignf(log1pf(fabsf(p1)), p1);
        p0 = qx - gkxB; p1 = qy - gkyB;
        float s0b = copysignf(log1pf(fabsf(p0)), p0);
        float s1b = copysignf(log1pf(fabsf(p1)), p1);

        // h1 fragments for both tiles: 4 kc x short8 each (32 VGPRs total)
        short8 hA[4], hB[4];
#pragma unroll
        for (int kc = 0; kc < 4; kc++) {
            f32x4 cu0 = *(const f32x4*)&coef[kc * 32 + quad * 8];
            f32x4 cu1 = *(const f32x4*)&coef[kc * 32 + quad * 8 + 4];
            f32x4 cv0 = *(const f32x4*)&coef[128 + kc * 32 + quad * 8];
            f32x4 cv1 = *(const f32x4*)&coef[128 + kc * 32 + quad * 8 + 4];
            f32x4 cb0 = *(const f32x4*)&coef[256 + kc * 32 + quad * 8];
            f32x4 cb1 = *(const f32x4*)&coef[256 + kc * 32 + quad * 8 + 4];
            u32x4 pa, pb;
#pragma unroll
            for (int j2 = 0; j2 < 4; j2++) {
                int e0 = 2 * j2, e1 = 2 * j2 + 1;
                float u0 = (e0 < 4) ? cu0[e0] : cu1[e0 - 4];
                float u1 = (e1 < 4) ? cu0[e1] : cu1[e1 - 4];
                float v0 = (e0 < 4) ? cv0[e0] : cv1[e0 - 4];
                float v1 = (e1 < 4) ? cv0[e1] : cv1[e1 - 4];
                float c0 = (e0 < 4) ? cb0[e0] : cb1[e0 - 4];
                float c1 = (e1 < 4) ? cb0[e1] : cb1[e1 - 4];
                // tile A (h >= 0 after relu, so +0x8000 round-half-up is safe)
                unsigned a0 = __builtin_bit_cast(unsigned,
                    fmaxf(fmaf(s0a, u0, fmaf(s1a, v0, c0)), 0.f)) + 0x8000u;
                unsigned a1 = __builtin_bit_cast(unsigned,
                    fmaxf(fmaf(s0a, u1, fmaf(s1a, v1, c1)), 0.f)) + 0x8000u;
                pa[j2] = __builtin_amdgcn_perm(a1, a0, 0x07060302);
                // tile B
                unsigned b0 = __builtin_bit_cast(unsigned,
                    fmaxf(fmaf(s0b, u0, fmaf(s1b, v0, c0)), 0.f)) + 0x8000u;
                unsigned b1_ = __builtin_bit_cast(unsigned,
                    fmaxf(fmaf(s0b, u1, fmaf(s1b, v1, c1)), 0.f)) + 0x8000u;
                pb[j2] = __builtin_amdgcn_perm(b1_, b0, 0x07060302);
            }
            hA[kc] = __builtin_bit_cast(short8, pa);
            hB[kc] = __builtin_bit_cast(short8, pb);
        }

        float psumA = 0.f, psumB = 0.f;
#pragma unroll 1
        for (int nt = 0; nt < 8; nt++) {
            f32x4 accA = (f32x4){0.f, 0.f, 0.f, 0.f};
            f32x4 accB = (f32x4){0.f, 0.f, 0.f, 0.f};
#pragma unroll
            for (int kc = 0; kc < 4; kc++) {
                short8 af = *(const short8*)(w2fs + (((nt * 4 + kc) * 64) + lane) * 8);
                accA = __builtin_amdgcn_mfma_f32_16x16x32_bf16(af, hA[kc], accA, 0, 0, 0);
                accB = __builtin_amdgcn_mfma_f32_16x16x32_bf16(af, hB[kc], accB, 0, 0, 0);
            }
            f32x4 b2q = *(const f32x4*)&coef[384 + nt * 16 + quad * 4];
            f32x4 w3q = *(const f32x4*)&coef[512 + nt * 16 + quad * 4];
#pragma unroll
            for (int r = 0; r < 4; r++) {
                psumA = fmaf(fmaxf(accA[r] + b2q[r], 0.f), w3q[r], psumA);
                psumB = fmaf(fmaxf(accB[r] + b2q[r], 0.f), w3q[r], psumB);
            }
        }
        psumA += __shfl_xor(psumA, 16);
        psumA += __shfl_xor(psumA, 32);
        psumB += __shfl_xor(psumB, 16);
        psumB += __shfl_xor(psumB, 32);
        if (quad == 0) {
            bias[(size_t)(p * 2 + 0) * 16 + l15] = psumA + bias3;
            bias[(size_t)(p * 2 + 1) * 16 + l15] = psumB + bias3;
        }
    }
}

// ---------------- K7: attention (bias precomputed) ----------------
__global__ __launch_bounds__(64) void k_attn(
    const float* __restrict__ q, const float* __restrict__ kk,
    const float* __restrict__ vv, const float* __restrict__ bias,
    float* __restrict__ ao) {
    __shared__ float ks[64 * 65];
    __shared__ float attn_s[64];
    int blk = blockIdx.x;
    int bg = blk >> 10;
    int i = blk & 1023;
    int b = bg >> 3, g = bg & 7;
    int j = threadIdx.x;

    for (int idx = j; idx < 4096; idx += 64)
        ks[(idx >> 6) * 65 + (idx & 63)] = kk[bg * 4096 + idx];
    __syncthreads();

    const float* qrow = q + (size_t)(b * CC + g * 64) * HWP + i;  // uniform
    float sim = 0.f;
#pragma unroll
    for (int d = 0; d < 64; d++) sim = fmaf(qrow[d * HWP], ks[j * 65 + d], sim);
    sim = sim * 0.125f + bias[(size_t)blk * 64 + j];

    float m = sim;
#pragma unroll
    for (int off = 32; off; off >>= 1) m = fmaxf(m, __shfl_xor(m, off));
    float p = expf(sim - m);
    float l = p;
#pragma unroll
    for (int off = 32; off; off >>= 1) l += __shfl_xor(l, off);
    attn_s[j] = p / l;
    __syncthreads();

    int d = j;
    float out = 0.f;
#pragma unroll
    for (int jj = 0; jj < 64; jj++)
        out = fmaf(attn_s[jj], vv[(size_t)(bg * 64 + jj) * 64 + d], out);
    ao[(size_t)(b * CC + g * 64 + d) * HWP + i] = out;
}

// ---------------- K8/K10/K11: tiled bf16-MFMA GEMM ----------------
// out[b][m][i] = epi( sum_k A[m][k] * B[b][k][i] + bias[m] )
// EPI 0: + resid, fp32 out.  EPI 1: gelu, bf16 out.  EPI 2: + resid, fp32 out.
template<int EPI, int KD, int MT, bool BBF>
__global__ __launch_bounds__(256) void k_gemm(
    const float* __restrict__ A, const void* __restrict__ Bp,
    const float* __restrict__ resid, const float* __restrict__ bias,
    void* __restrict__ outp) {
    constexpr int MM = MT * 64;
    __shared__ __align__(16) short As[64][72];
    __shared__ __align__(16) short Bs[64][72];
    int tid = threadIdx.x;
    int blk = blockIdx.x;
    int mt = blk & (MT - 1);
    int nb = blk / MT;              // 0..31
    int bb = nb >> 4, nt = nb & 15;
    int m0 = mt * 64, i0 = nt * 64;
    int lane = tid & 63, wv = tid >> 6;
    int wm = (wv >> 1) * 32, wn = (wv & 1) * 32;
    int l15 = lane & 15, quad = lane >> 4;
    const float* Af = A + (size_t)m0 * KD;
    const float* Bf = (const float*)Bp;
    const unsigned short* Bh = (const unsigned short*)Bp;

    f32x4 acc[2][2];
#pragma unroll
    for (int a = 0; a < 2; a++)
#pragma unroll
        for (int c = 0; c < 2; c++) acc[a][c] = (f32x4){0.f, 0.f, 0.f, 0.f};

    for (int k0 = 0; k0 < KD; k0 += 64) {
        __syncthreads();
        {
            int kk4 = (tid & 15) * 4;
            int myb = tid >> 4;               // 0..15
#pragma unroll
            for (int p = 0; p < 4; p++) {
                int my = myb + p * 16;
                f32x4 v = *(const f32x4*)(Af + (size_t)my * KD + k0 + kk4);
                s16x4 s = {f2bf(v.x), f2bf(v.y), f2bf(v.z), f2bf(v.w)};
                *(s16x4*)&As[my][kk4] = s;
            }
        }
        {
            int i4 = (tid & 15) * 4;
            int kyb = tid >> 4;
#pragma unroll
            for (int p = 0; p < 4; p++) {
                int ky = kyb + p * 16;
                size_t goff = (size_t)bb * KD * HWP + (size_t)(k0 + ky) * HWP + i0 + i4;
                if (BBF) {
                    u16x4 v = *(const u16x4*)(Bh + goff);
                    Bs[i4 + 0][ky] = (short)v.x;
                    Bs[i4 + 1][ky] = (short)v.y;
                    Bs[i4 + 2][ky] = (short)v.z;
                    Bs[i4 + 3][ky] = (short)v.w;
                } else {
                    f32x4 v = *(const f32x4*)(Bf + goff);
                    Bs[i4 + 0][ky] = f2bf(v.x);
                    Bs[i4 + 1][ky] = f2bf(v.y);
                    Bs[i4 + 2][ky] = f2bf(v.z);
                    Bs[i4 + 3][ky] = f2bf(v.w);
                }
            }
        }
        __syncthreads();
#pragma unroll
        for (int ks = 0; ks < 2; ks++) {
            short8 af0 = *(const short8*)&As[wm + l15][ks * 32 + quad * 8];
            short8 af1 = *(const short8*)&As[wm + 16 + l15][ks * 32 + quad * 8];
            short8 bf0 = *(const short8*)&Bs[wn + l15][ks * 32 + quad * 8];
            short8 bf1 = *(const short8*)&Bs[wn + 16 + l15][ks * 32 + quad * 8];
            acc[0][0] = __builtin_amdgcn_mfma_f32_16x16x32_bf16(af0, bf0, acc[0][0], 0, 0, 0);
            acc[0][1] = __builtin_amdgcn_mfma_f32_16x16x32_bf16(af0, bf1, acc[0][1], 0, 0, 0);
            acc[1][0] = __builtin_amdgcn_mfma_f32_16x16x32_bf16(af1, bf0, acc[1][0], 0, 0, 0);
            acc[1][1] = __builtin_amdgcn_mfma_f32_16x16x32_bf16(af1, bf1, acc[1][1], 0, 0, 0);
        }
    }

    float* outF = (float*)outp;
    unsigned short* outH = (unsigned short*)outp;
#pragma unroll
    for (int im = 0; im < 2; im++) {
#pragma unroll
        for (int r = 0; r < 4; r++) {
            int m = m0 + wm + im * 16 + quad * 4 + r;
            float bv = bias[m];
#pragma unroll
            for (int in_ = 0; in_ < 2; in_++) {
                int n = i0 + wn + in_ * 16 + l15;
                size_t idx = ((size_t)bb * MM + m) * HWP + n;
                float v = acc[im][in_][r] + bv;
                if constexpr (EPI == 1) {
                    float ge = 0.5f * v * (1.0f + erff(v * 0.7071067811865475f));
                    outH[idx] = (unsigned short)f2bf(ge);
                } else {
                    outF[idx] = v + resid[idx];
                }
            }
        }
    }
}

// ---------------- K9: BN2 ----------------
__global__ void k_bn2(const float* __restrict__ xo, const float* __restrict__ g,
                      const float* __restrict__ b, float* __restrict__ xn2) {
    int idx = blockIdx.x * 256 + threadIdx.x;
    int c = (idx >> 10) & (CC - 1);
    float s = g[c] / sqrtf(1.0f + EPS);
    xn2[idx] = xo[idx] * s + b[c];
}

extern "C" void kernel_launch(void* const* d_in, const int* in_sizes, int n_in,
                              void* d_out, int out_size, void* d_ws, size_t ws_size,
                              hipStream_t stream) {
    const float* x      = (const float*)d_in[0];
    const float* bn1_g  = (const float*)d_in[1];
    const float* bn1_b  = (const float*)d_in[2];
    const float* bn2_g  = (const float*)d_in[3];
    const float* bn2_b  = (const float*)d_in[4];
    const float* qw     = (const float*)d_in[5];
    const float* kw     = (const float*)d_in[6];
    const float* vw     = (const float*)d_in[7];
    const float* out_w  = (const float*)d_in[8];
    const float* out_b  = (const float*)d_in[9];
    const float* off_dw_w = (const float*)d_in[10];
    const float* off_dw_b = (const float*)d_in[11];
    const float* off_pw_w = (const float*)d_in[12];
    const float* cpb_w1 = (const float*)d_in[13];
    const float* cpb_b1 = (const float*)d_in[14];
    const float* cpb_w2 = (const float*)d_in[15];
    const float* cpb_b2 = (const float*)d_in[16];
    const float* cpb_w3 = (const float*)d_in[17];
    const float* cpb_b3 = (const float*)d_in[18];
    const float* mlp_w1 = (const float*)d_in[19];
    const float* mlp_b1 = (const float*)d_in[20];
    const float* mlp_w2 = (const float*)d_in[21];
    const float* mlp_b2 = (const float*)d_in[22];

    float* ws = (float*)d_ws;
    // workspace layout (floats)
    float* xn    = ws + 0;            // 1,048,576 (reused as xn2)
    float* q     = ws + 1048576;      // 1,048,576
    float* vgrid = ws + 2097152;      // 2,048
    float* kv    = ws + 2099200;      // 65,536
    float* kk    = ws + 2164736;      // 65,536
    float* vv    = ws + 2230272;      // 65,536
    unsigned short* w2p = (unsigned short*)(ws + 2295808);  // 16,384 bf16 (8,192 floats)
    float* ao    = ws + 2312192;      // 1,048,576
    float* xo    = ws + 3360768;      // 1,048,576
    float* h1of  = ws + 4409344;      // region reused: bias (1M floats) then h1o bf16
    float* biasb = h1of;              // 1,048,576 floats — consumed by k_attn before k_mlp1 writes h1o
    unsigned short* h1o = (unsigned short*)h1of;  // 4,194,304 bf16

    hipLaunchKernelGGL(k_bn1, dim3(4096), dim3(256), 0, stream, x, bn1_g, bn1_b, xn);
    hipLaunchKernelGGL(k_qconv, dim3(1024, 4), dim3(256), 0, stream, xn, qw, q);
    hipLaunchKernelGGL(k_off, dim3(1024), dim3(64), 0, stream, q, off_dw_w, off_dw_b, off_pw_w, vgrid);
    hipLaunchKernelGGL(k_sample, dim3(256), dim3(256), 0, stream, xn, vgrid, kv);
    hipLaunchKernelGGL(k_kvconv, dim3(256), dim3(256), 0, stream, kv, kw, vw, kk, vv);
    hipLaunchKernelGGL(k_w2pack, dim3(64), dim3(256), 0, stream, cpb_w2, w2p);
    hipLaunchKernelGGL(k_cpb, dim3(2048), dim3(256), 0, stream,
                       vgrid, w2p, cpb_w1, cpb_b1, cpb_b2, cpb_w3, cpb_b3, biasb);
    hipLaunchKernelGGL(k_attn, dim3(16384), dim3(64), 0, stream, q, kk, vv, biasb, ao);
    // out projection: M=512 (MT=8), K=512, B=ao fp32, resid=x -> xo
    k_gemm<0, 512, 8, false><<<dim3(256), dim3(256), 0, stream>>>(out_w, ao, x, out_b, xo);
    hipLaunchKernelGGL(k_bn2, dim3(4096), dim3(256), 0, stream, xo, bn2_g, bn2_b, xn);
    // MLP1: M=2048 (MT=32), K=512, B=xn fp32, gelu -> h1o (bf16)
    k_gemm<1, 512, 32, false><<<dim3(1024), dim3(256), 0, stream>>>(mlp_w1, xn, nullptr, mlp_b1, h1o);
    // MLP2: M=512 (MT=8), K=2048, B=h1o bf16, resid=xo -> d_out
    k_gemm<2, 2048, 8, true><<<dim3(256), dim3(256), 0, stream>>>(mlp_w2, h1o, xo, mlp_b2, d_out);
}

// Round 6
// 288.247 us; speedup vs baseline: 4.9237x; 1.2095x over previous
//
#include <hip/hip_runtime.h>
#include <hip/hip_bf16.h>
#include <math.h>

// Problem constants
#define BB 2
#define CC 512
#define HH 32
#define WW 32
#define HWP 1024      // H*W
#define GG 8
#define DH 64
#define HD 8
#define WD 8
#define JJ 64         // HD*WD
#define BG 16         // BB*GG
#define EPS 1e-5f

typedef __attribute__((ext_vector_type(8))) short short8;
typedef __attribute__((ext_vector_type(4))) short s16x4;
typedef __attribute__((ext_vector_type(4))) float f32x4;
typedef __attribute__((ext_vector_type(4))) unsigned short u16x4;
typedef __attribute__((ext_vector_type(4))) unsigned int u32x4;

// RNE float -> bf16 bits
static __device__ __forceinline__ short f2bf(float x) {
    unsigned u = __builtin_bit_cast(unsigned, x);
    u += 0x7FFFu + ((u >> 16) & 1u);
    return (short)(u >> 16);
}

// ---------------- K2: q grouped 1x1 conv (BN1 folded inline) ----------------
__global__ void k_qconv(const float* __restrict__ x, const float* __restrict__ g1,
                        const float* __restrict__ b1, const float* __restrict__ qw,
                        float* __restrict__ q) {
    int o_lin = blockIdx.x;                  // b*512 + g*64 + o
    int i = blockIdx.y * 256 + threadIdx.x;
    int b = o_lin >> 9;
    int g = (o_lin >> 6) & 7;
    int o = o_lin & 63;
    const float invs = 1.0f / sqrtf(1.0f + EPS);
    const float* wrow = qw + (g * 64 + o) * 64;
    const float* xin = x + (size_t)(b * CC + g * 64) * HWP + i;
    const float* gs = g1 + g * 64;
    const float* bs = b1 + g * 64;
    float acc = 0.f;
#pragma unroll
    for (int c = 0; c < 64; c++) {
        float xv = fmaf(xin[c * HWP], gs[c] * invs, bs[c]);   // BN1
        acc = fmaf(xv, wrow[c], acc);
    }
    q[(size_t)o_lin * HWP + i] = acc;
}

// ---------------- K3: offsets -> vgrid ----------------
__global__ void k_off(const float* __restrict__ q, const float* __restrict__ dww,
                      const float* __restrict__ dwb, const float* __restrict__ pw,
                      float* __restrict__ vgrid) {
    int blk = blockIdx.x;          // bg*64 + hd*8 + wd
    int bg = blk >> 6;
    int hd = (blk >> 3) & 7;
    int wd = blk & 7;
    int ch = threadIdx.x;
    const float* qch = q + (size_t)(bg * 64 + ch) * HWP;
    float acc = 0.f;
#pragma unroll
    for (int kh = 0; kh < 6; kh++) {
        int hin = hd * 4 - 1 + kh;
        if (hin < 0 || hin >= HH) continue;
#pragma unroll
        for (int kw_ = 0; kw_ < 6; kw_++) {
            int win = wd * 4 - 1 + kw_;
            if (win < 0 || win >= WW) continue;
            acc = fmaf(qch[hin * WW + win], dww[ch * 36 + kh * 6 + kw_], acc);
        }
    }
    acc += dwb[ch];
    float ge = 0.5f * acc * (1.0f + erff(acc * 0.7071067811865475f));
    float p0 = ge * pw[ch];
    float p1 = ge * pw[64 + ch];
#pragma unroll
    for (int off = 32; off; off >>= 1) {
        p0 += __shfl_xor(p0, off);
        p1 += __shfl_xor(p1, off);
    }
    if (ch == 0) {
        float off0 = tanhf(p0) * 4.0f;
        float off1 = tanhf(p1) * 4.0f;
        float vx = (float)wd + off0;
        float vy = (float)hd + off1;
        float nx = 2.0f * vx / 7.0f - 1.0f;
        float ny = 2.0f * vy / 7.0f - 1.0f;
        vgrid[blk * 2] = nx;
        vgrid[blk * 2 + 1] = ny;
    }
}

// ---------------- K4: grid_sample (BN1 folded: s*sum(w*x) + b*sum(w*valid)) ----------------
__global__ void k_sample(const float* __restrict__ x, const float* __restrict__ g1,
                         const float* __restrict__ b1, const float* __restrict__ vgrid,
                         float* __restrict__ kv) {
    int tid = blockIdx.x * 256 + threadIdx.x;   // 65536
    int bg = tid >> 12;
    int ch = (tid >> 6) & 63;
    int j = tid & 63;
    int cg = (bg & 7) * 64 + ch;
    int bb = bg >> 3;
    const float invs = 1.0f / sqrtf(1.0f + EPS);
    float s = g1[cg] * invs;
    float bv = b1[cg];
    float nx = vgrid[(bg * 64 + j) * 2];
    float ny = vgrid[(bg * 64 + j) * 2 + 1];
    float gx = (nx + 1.0f) * 16.0f - 0.5f;
    float gy = (ny + 1.0f) * 16.0f - 0.5f;
    float x0f = floorf(gx), y0f = floorf(gy);
    float wx = gx - x0f, wy = gy - y0f;
    int x0 = (int)x0f, y0 = (int)y0f;
    const float* im = x + (size_t)(bb * CC + cg) * HWP;
    float sx = 0.f, sw = 0.f;
    float w00 = (1 - wx) * (1 - wy), w01 = wx * (1 - wy);
    float w10 = (1 - wx) * wy, w11 = wx * wy;
    if (x0 >= 0 && x0 < WW && y0 >= 0 && y0 < HH)         { sx += w00 * im[y0 * WW + x0];           sw += w00; }
    if (x0 + 1 >= 0 && x0 + 1 < WW && y0 >= 0 && y0 < HH) { sx += w01 * im[y0 * WW + x0 + 1];       sw += w01; }
    if (x0 >= 0 && x0 < WW && y0 + 1 >= 0 && y0 + 1 < HH) { sx += w10 * im[(y0 + 1) * WW + x0];     sw += w10; }
    if (x0 + 1 >= 0 && x0 + 1 < WW && y0 + 1 >= 0 && y0 + 1 < HH) { sx += w11 * im[(y0 + 1) * WW + x0 + 1]; sw += w11; }
    kv[tid] = s * sx + bv * sw;
}

// ---------------- K5: k/v grouped 1x1 convs ----------------
__global__ void k_kvconv(const float* __restrict__ kv, const float* __restrict__ kw,
                         const float* __restrict__ vw, float* __restrict__ kk,
                         float* __restrict__ vv) {
    int tid = blockIdx.x * 256 + threadIdx.x;   // 65536
    int bg = tid >> 12;
    int j = (tid >> 6) & 63;
    int o = tid & 63;
    int g = bg & 7;
    const float* kvp = kv + (size_t)bg * 4096 + j;   // [bg][c][j]
    const float* kwr = kw + (g * 64 + o) * 64;
    const float* vwr = vw + (g * 64 + o) * 64;
    float ak = 0.f, av = 0.f;
#pragma unroll
    for (int c = 0; c < 64; c++) {
        float t = kvp[c * 64];
        ak = fmaf(t, kwr[c], ak);
        av = fmaf(t, vwr[c], av);
    }
    kk[tid] = ak;
    vv[tid] = av;
}

// ---------------- K5b: pre-pack W2 into bf16 fragment order ----------------
__global__ void k_w2pack(const float* __restrict__ w2, unsigned short* __restrict__ w2p) {
    int idx = blockIdx.x * 256 + threadIdx.x;   // 16384
    int k = idx >> 7, n = idx & 127;
    int dest = ((((n >> 4) * 4 + (k >> 5)) * 64) + (((k >> 3) & 3) * 16) + (n & 15)) * 8 + (k & 7);
    w2p[dest] = (unsigned short)f2bf(w2[idx]);
}

// ---------------- K6: CPB bias MLP via bf16 MFMA (v3, frozen) ----------------
__global__ __launch_bounds__(256) void k_cpb(
    const float* __restrict__ vgrid, const unsigned short* __restrict__ w2p,
    const float* __restrict__ w1, const float* __restrict__ b1,
    const float* __restrict__ b2, const float* __restrict__ w3,
    const float* __restrict__ b3, float* __restrict__ bias) {
    __shared__ __align__(16) short w2fs[16384];
    __shared__ __align__(16) float coef[640];
    int tid = threadIdx.x;
    {
        const u32x4* src = (const u32x4*)w2p;
        u32x4* dst = (u32x4*)w2fs;
        for (int c = tid; c < 2048; c += 256) dst[c] = src[c];
    }
    if (tid < 256) coef[tid] = w1[tid];
    else if (tid < 384) coef[tid] = b1[tid - 256];
    else if (tid < 512) coef[tid] = b2[tid - 384];
    if (tid >= 128 && tid < 256) coef[512 + tid - 128] = w3[tid - 128];
    float bias3 = b3[0];
    __syncthreads();

    int lane = tid & 63;
    int wv = tid >> 6;
    int l15 = lane & 15;
    int quad = lane >> 4;

#pragma unroll 1
    for (int it = 0; it < 4; it++) {
        int p = (blockIdx.x * 4 + it) * 4 + wv;
        int bg = p >> 11;
        int i = (p >> 1) & 1023;
        int jbase = (p & 1) * 32;
        int hi = i >> 5, wi = i & 31;
        float qx = 2.0f * (float)wi / 31.0f - 1.0f;
        float qy = 2.0f * (float)hi / 31.0f - 1.0f;

        int jA = jbase + l15;
        float gkxA = vgrid[(bg * 64 + jA) * 2];
        float gkyA = vgrid[(bg * 64 + jA) * 2 + 1];
        float gkxB = vgrid[(bg * 64 + jA + 16) * 2];
        float gkyB = vgrid[(bg * 64 + jA + 16) * 2 + 1];
        float p0 = qx - gkxA, p1 = qy - gkyA;
        float s0a = copysignf(log1pf(fabsf(p0)), p0);
        float s1a = copysignf(log1pf(fabsf(p1)), p1);
        p0 = qx - gkxB; p1 = qy - gkyB;
        float s0b = copysignf(log1pf(fabsf(p0)), p0);
        float s1b = copysignf(log1pf(fabsf(p1)), p1);

        short8 hA[4], hB[4];
#pragma unroll
        for (int kc = 0; kc < 4; kc++) {
            f32x4 cu0 = *(const f32x4*)&coef[kc * 32 + quad * 8];
            f32x4 cu1 = *(const f32x4*)&coef[kc * 32 + quad * 8 + 4];
            f32x4 cv0 = *(const f32x4*)&coef[128 + kc * 32 + quad * 8];
            f32x4 cv1 = *(const f32x4*)&coef[128 + kc * 32 + quad * 8 + 4];
            f32x4 cb0 = *(const f32x4*)&coef[256 + kc * 32 + quad * 8];
            f32x4 cb1 = *(const f32x4*)&coef[256 + kc * 32 + quad * 8 + 4];
            u32x4 pa, pb;
#pragma unroll
            for (int j2 = 0; j2 < 4; j2++) {
                int e0 = 2 * j2, e1 = 2 * j2 + 1;
                float u0 = (e0 < 4) ? cu0[e0] : cu1[e0 - 4];
                float u1 = (e1 < 4) ? cu0[e1] : cu1[e1 - 4];
                float v0 = (e0 < 4) ? cv0[e0] : cv1[e0 - 4];
                float v1 = (e1 < 4) ? cv0[e1] : cv1[e1 - 4];
                float c0 = (e0 < 4) ? cb0[e0] : cb1[e0 - 4];
                float c1 = (e1 < 4) ? cb0[e1] : cb1[e1 - 4];
                unsigned a0 = __builtin_bit_cast(unsigned,
                    fmaxf(fmaf(s0a, u0, fmaf(s1a, v0, c0)), 0.f)) + 0x8000u;
                unsigned a1 = __builtin_bit_cast(unsigned,
                    fmaxf(fmaf(s0a, u1, fmaf(s1a, v1, c1)), 0.f)) + 0x8000u;
                pa[j2] = __builtin_amdgcn_perm(a1, a0, 0x07060302);
                unsigned b0 = __builtin_bit_cast(unsigned,
                    fmaxf(fmaf(s0b, u0, fmaf(s1b, v0, c0)), 0.f)) + 0x8000u;
                unsigned b1_ = __builtin_bit_cast(unsigned,
                    fmaxf(fmaf(s0b, u1, fmaf(s1b, v1, c1)), 0.f)) + 0x8000u;
                pb[j2] = __builtin_amdgcn_perm(b1_, b0, 0x07060302);
            }
            hA[kc] = __builtin_bit_cast(short8, pa);
            hB[kc] = __builtin_bit_cast(short8, pb);
        }

        float psumA = 0.f, psumB = 0.f;
#pragma unroll 1
        for (int nt = 0; nt < 8; nt++) {
            f32x4 accA = (f32x4){0.f, 0.f, 0.f, 0.f};
            f32x4 accB = (f32x4){0.f, 0.f, 0.f, 0.f};
#pragma unroll
            for (int kc = 0; kc < 4; kc++) {
                short8 af = *(const short8*)(w2fs + (((nt * 4 + kc) * 64) + lane) * 8);
                accA = __builtin_amdgcn_mfma_f32_16x16x32_bf16(af, hA[kc], accA, 0, 0, 0);
                accB = __builtin_amdgcn_mfma_f32_16x16x32_bf16(af, hB[kc], accB, 0, 0, 0);
            }
            f32x4 b2q = *(const f32x4*)&coef[384 + nt * 16 + quad * 4];
            f32x4 w3q = *(const f32x4*)&coef[512 + nt * 16 + quad * 4];
#pragma unroll
            for (int r = 0; r < 4; r++) {
                psumA = fmaf(fmaxf(accA[r] + b2q[r], 0.f), w3q[r], psumA);
                psumB = fmaf(fmaxf(accB[r] + b2q[r], 0.f), w3q[r], psumB);
            }
        }
        psumA += __shfl_xor(psumA, 16);
        psumA += __shfl_xor(psumA, 32);
        psumB += __shfl_xor(psumB, 16);
        psumB += __shfl_xor(psumB, 32);
        if (quad == 0) {
            bias[(size_t)(p * 2 + 0) * 16 + l15] = psumA + bias3;
            bias[(size_t)(p * 2 + 1) * 16 + l15] = psumB + bias3;
        }
    }
}

// ---------------- K7: attention via MFMA (flash-style, J=64 fits one tile row) ----------------
// grid: 256 blocks = (bg, 64-i chunk); 256 threads = 4 waves x 16 i rows.
// ao written as bf16 (consumed by the bf16 GEMM outproj).
__global__ __launch_bounds__(256) void k_attn(
    const float* __restrict__ q, const float* __restrict__ kk,
    const float* __restrict__ vv, const float* __restrict__ bias,
    unsigned short* __restrict__ ao) {
    __shared__ __align__(16) short Ks[64][72];    // [j][d] bf16, pad 8
    __shared__ __align__(16) short Vt[64][72];    // [d][j] bf16 (transposed)
    __shared__ __align__(16) short Qs[64][72];    // [i][d] bf16 (scale folded)
    __shared__ __align__(16) short Ps[4][16][72]; // per-wave P [i16][j] bf16
    int blk = blockIdx.x;
    int bg = blk >> 4;
    int chunk = blk & 15;
    int i0 = chunk * 64;
    int b = bg >> 3, g = bg & 7;
    int tid = threadIdx.x, lane = tid & 63, wv = tid >> 6;
    int l15 = lane & 15, quad = lane >> 4;

    const float* kbase = kk + (size_t)bg * 4096;
    const float* vbase = vv + (size_t)bg * 4096;
#pragma unroll
    for (int it = 0; it < 4; it++) {
        int e4 = it * 1024 + tid * 4;
        int j = e4 >> 6, d = e4 & 63;
        f32x4 k4 = *(const f32x4*)(kbase + e4);
        s16x4 s = {f2bf(k4.x), f2bf(k4.y), f2bf(k4.z), f2bf(k4.w)};
        *(s16x4*)&Ks[j][d] = s;
        f32x4 v4 = *(const f32x4*)(vbase + e4);
        Vt[d + 0][j] = f2bf(v4.x);
        Vt[d + 1][j] = f2bf(v4.y);
        Vt[d + 2][j] = f2bf(v4.z);
        Vt[d + 3][j] = f2bf(v4.w);
    }
    const float* qbase = q + (size_t)(b * CC + g * 64) * HWP + i0;
#pragma unroll
    for (int it = 0; it < 4; it++) {
        int e4 = it * 1024 + tid * 4;
        int d = e4 >> 6, i = e4 & 63;
        f32x4 q4 = *(const f32x4*)(qbase + (size_t)d * HWP + i);
        Qs[i + 0][d] = f2bf(q4.x * 0.125f);   // scale = DH^-0.5, exact pow2
        Qs[i + 1][d] = f2bf(q4.y * 0.125f);
        Qs[i + 2][d] = f2bf(q4.z * 0.125f);
        Qs[i + 3][d] = f2bf(q4.w * 0.125f);
    }
    __syncthreads();

    int iw = wv * 16;
    f32x4 Sacc[4];
#pragma unroll
    for (int nt = 0; nt < 4; nt++) Sacc[nt] = (f32x4){0.f, 0.f, 0.f, 0.f};
#pragma unroll
    for (int ks = 0; ks < 2; ks++) {
        short8 aq = *(const short8*)&Qs[iw + l15][quad * 8 + ks * 32];
#pragma unroll
        for (int nt = 0; nt < 4; nt++) {
            short8 bk = *(const short8*)&Ks[nt * 16 + l15][quad * 8 + ks * 32];
            Sacc[nt] = __builtin_amdgcn_mfma_f32_16x16x32_bf16(aq, bk, Sacc[nt], 0, 0, 0);
        }
    }
    // S[i = iw+quad*4+r][j = nt*16+l15] in Sacc[nt][r]; add bias, softmax over j
    const float* bp = bias + ((size_t)bg * 1024 + i0 + iw + quad * 4) * 64 + l15;
    float Sv[4][4];
#pragma unroll
    for (int nt = 0; nt < 4; nt++)
#pragma unroll
        for (int r = 0; r < 4; r++)
            Sv[nt][r] = Sacc[nt][r] + bp[r * 64 + nt * 16];
#pragma unroll
    for (int r = 0; r < 4; r++) {
        float m = fmaxf(fmaxf(Sv[0][r], Sv[1][r]), fmaxf(Sv[2][r], Sv[3][r]));
        m = fmaxf(m, __shfl_xor(m, 1));
        m = fmaxf(m, __shfl_xor(m, 2));
        m = fmaxf(m, __shfl_xor(m, 4));
        m = fmaxf(m, __shfl_xor(m, 8));
        float l = 0.f;
#pragma unroll
        for (int nt = 0; nt < 4; nt++) { Sv[nt][r] = expf(Sv[nt][r] - m); l += Sv[nt][r]; }
        l += __shfl_xor(l, 1);
        l += __shfl_xor(l, 2);
        l += __shfl_xor(l, 4);
        l += __shfl_xor(l, 8);
        float inv = 1.0f / l;
#pragma unroll
        for (int nt = 0; nt < 4; nt++)
            Ps[wv][quad * 4 + r][nt * 16 + l15] = f2bf(Sv[nt][r] * inv);
    }
    // same-wave LDS produce->consume: lgkmcnt handles ordering, no barrier needed
    f32x4 Oacc[4];
#pragma unroll
    for (int nt = 0; nt < 4; nt++) Oacc[nt] = (f32x4){0.f, 0.f, 0.f, 0.f};
#pragma unroll
    for (int ks = 0; ks < 2; ks++) {
        short8 ap = *(const short8*)&Ps[wv][l15][quad * 8 + ks * 32];
#pragma unroll
        for (int nt = 0; nt < 4; nt++) {
            short8 bv = *(const short8*)&Vt[nt * 16 + l15][quad * 8 + ks * 32];
            Oacc[nt] = __builtin_amdgcn_mfma_f32_16x16x32_bf16(ap, bv, Oacc[nt], 0, 0, 0);
        }
    }
    // O[i = iw+quad*4+r][d = nt*16+l15] -> ao[(b*512+g*64+d)*1024 + i] as bf16
#pragma unroll
    for (int nt = 0; nt < 4; nt++)
#pragma unroll
        for (int r = 0; r < 4; r++) {
            int d = nt * 16 + l15;
            int i = i0 + iw + quad * 4 + r;
            ao[(size_t)(b * CC + g * 64 + d) * HWP + i] = (unsigned short)f2bf(Oacc[nt][r]);
        }
}

// ---------------- K8/K10/K11: tiled bf16-MFMA GEMM ----------------
// out[b][m][i] = epi( sum_k A[m][k] * B_eff[b][k][i] + bias[m] )
// B_eff = BN ? (B*scale[k]+shift[k]) : B.  EPI 0/2: +resid fp32 out. EPI 1: gelu bf16 out.
template<int EPI, int KD, int MT, bool BBF, bool BN>
__global__ __launch_bounds__(256) void k_gemm(
    const float* __restrict__ A, const void* __restrict__ Bp,
    const float* __restrict__ resid, const float* __restrict__ bias,
    void* __restrict__ outp,
    const float* __restrict__ bns, const float* __restrict__ bnb) {
    constexpr int MM = MT * 64;
    __shared__ __align__(16) short As[64][72];
    __shared__ __align__(16) short Bs[64][72];
    int tid = threadIdx.x;
    int blk = blockIdx.x;
    int mt = blk & (MT - 1);
    int nb = blk / MT;              // 0..31
    int bb = nb >> 4, nt = nb & 15;
    int m0 = mt * 64, i0 = nt * 64;
    int lane = tid & 63, wv = tid >> 6;
    int wm = (wv >> 1) * 32, wn = (wv & 1) * 32;
    int l15 = lane & 15, quad = lane >> 4;
    const float* Af = A + (size_t)m0 * KD;
    const float* Bf = (const float*)Bp;
    const unsigned short* Bh = (const unsigned short*)Bp;
    const float invs = 1.0f / sqrtf(1.0f + EPS);

    f32x4 acc[2][2];
#pragma unroll
    for (int a = 0; a < 2; a++)
#pragma unroll
        for (int c = 0; c < 2; c++) acc[a][c] = (f32x4){0.f, 0.f, 0.f, 0.f};

    for (int k0 = 0; k0 < KD; k0 += 64) {
        __syncthreads();
        {
            int kk4 = (tid & 15) * 4;
            int myb = tid >> 4;               // 0..15
#pragma unroll
            for (int p = 0; p < 4; p++) {
                int my = myb + p * 16;
                f32x4 v = *(const f32x4*)(Af + (size_t)my * KD + k0 + kk4);
                s16x4 s = {f2bf(v.x), f2bf(v.y), f2bf(v.z), f2bf(v.w)};
                *(s16x4*)&As[my][kk4] = s;
            }
        }
        {
            int i4 = (tid & 15) * 4;
            int kyb = tid >> 4;
#pragma unroll
            for (int p = 0; p < 4; p++) {
                int ky = kyb + p * 16;
                size_t goff = (size_t)bb * KD * HWP + (size_t)(k0 + ky) * HWP + i0 + i4;
                if (BBF) {
                    u16x4 v = *(const u16x4*)(Bh + goff);
                    Bs[i4 + 0][ky] = (short)v.x;
                    Bs[i4 + 1][ky] = (short)v.y;
                    Bs[i4 + 2][ky] = (short)v.z;
                    Bs[i4 + 3][ky] = (short)v.w;
                } else {
                    f32x4 v = *(const f32x4*)(Bf + goff);
                    if (BN) {
                        float sc = bns[k0 + ky] * invs;
                        float sh = bnb[k0 + ky];
                        v.x = fmaf(v.x, sc, sh);
                        v.y = fmaf(v.y, sc, sh);
                        v.z = fmaf(v.z, sc, sh);
                        v.w = fmaf(v.w, sc, sh);
                    }
                    Bs[i4 + 0][ky] = f2bf(v.x);
                    Bs[i4 + 1][ky] = f2bf(v.y);
                    Bs[i4 + 2][ky] = f2bf(v.z);
                    Bs[i4 + 3][ky] = f2bf(v.w);
                }
            }
        }
        __syncthreads();
#pragma unroll
        for (int ks = 0; ks < 2; ks++) {
            short8 af0 = *(const short8*)&As[wm + l15][ks * 32 + quad * 8];
            short8 af1 = *(const short8*)&As[wm + 16 + l15][ks * 32 + quad * 8];
            short8 bf0 = *(const short8*)&Bs[wn + l15][ks * 32 + quad * 8];
            short8 bf1 = *(const short8*)&Bs[wn + 16 + l15][ks * 32 + quad * 8];
            acc[0][0] = __builtin_amdgcn_mfma_f32_16x16x32_bf16(af0, bf0, acc[0][0], 0, 0, 0);
            acc[0][1] = __builtin_amdgcn_mfma_f32_16x16x32_bf16(af0, bf1, acc[0][1], 0, 0, 0);
            acc[1][0] = __builtin_amdgcn_mfma_f32_16x16x32_bf16(af1, bf0, acc[1][0], 0, 0, 0);
            acc[1][1] = __builtin_amdgcn_mfma_f32_16x16x32_bf16(af1, bf1, acc[1][1], 0, 0, 0);
        }
    }

    float* outF = (float*)outp;
    unsigned short* outH = (unsigned short*)outp;
#pragma unroll
    for (int im = 0; im < 2; im++) {
#pragma unroll
        for (int r = 0; r < 4; r++) {
            int m = m0 + wm + im * 16 + quad * 4 + r;
            float bv = bias[m];
#pragma unroll
            for (int in_ = 0; in_ < 2; in_++) {
                int n = i0 + wn + in_ * 16 + l15;
                size_t idx = ((size_t)bb * MM + m) * HWP + n;
                float v = acc[im][in_][r] + bv;
                if constexpr (EPI == 1) {
                    float ge = 0.5f * v * (1.0f + erff(v * 0.7071067811865475f));
                    outH[idx] = (unsigned short)f2bf(ge);
                } else {
                    outF[idx] = v + resid[idx];
                }
            }
        }
    }
}

extern "C" void kernel_launch(void* const* d_in, const int* in_sizes, int n_in,
                              void* d_out, int out_size, void* d_ws, size_t ws_size,
                              hipStream_t stream) {
    const float* x      = (const float*)d_in[0];
    const float* bn1_g  = (const float*)d_in[1];
    const float* bn1_b  = (const float*)d_in[2];
    const float* bn2_g  = (const float*)d_in[3];
    const float* bn2_b  = (const float*)d_in[4];
    const float* qw     = (const float*)d_in[5];
    const float* kw     = (const float*)d_in[6];
    const float* vw     = (const float*)d_in[7];
    const float* out_w  = (const float*)d_in[8];
    const float* out_b  = (const float*)d_in[9];
    const float* off_dw_w = (const float*)d_in[10];
    const float* off_dw_b = (const float*)d_in[11];
    const float* off_pw_w = (const float*)d_in[12];
    const float* cpb_w1 = (const float*)d_in[13];
    const float* cpb_b1 = (const float*)d_in[14];
    const float* cpb_w2 = (const float*)d_in[15];
    const float* cpb_b2 = (const float*)d_in[16];
    const float* cpb_w3 = (const float*)d_in[17];
    const float* cpb_b3 = (const float*)d_in[18];
    const float* mlp_w1 = (const float*)d_in[19];
    const float* mlp_b1 = (const float*)d_in[20];
    const float* mlp_w2 = (const float*)d_in[21];
    const float* mlp_b2 = (const float*)d_in[22];

    float* ws = (float*)d_ws;
    // workspace layout (floats)
    float* q     = ws + 1048576;      // 1,048,576
    float* vgrid = ws + 2097152;      // 2,048
    float* kv    = ws + 2099200;      // 65,536
    float* kk    = ws + 2164736;      // 65,536
    float* vv    = ws + 2230272;      // 65,536
    unsigned short* w2p = (unsigned short*)(ws + 2295808);  // 16,384 bf16
    unsigned short* ao  = (unsigned short*)(ws + 2312192);  // 1,048,576 bf16
    float* xo    = ws + 3360768;      // 1,048,576
    float* h1of  = ws + 4409344;      // bias (1M floats), then h1o bf16 (4M)
    float* biasb = h1of;              // consumed by k_attn before k_mlp1 writes h1o
    unsigned short* h1o = (unsigned short*)h1of;

    hipLaunchKernelGGL(k_qconv, dim3(1024, 4), dim3(256), 0, stream, x, bn1_g, bn1_b, qw, q);
    hipLaunchKernelGGL(k_off, dim3(1024), dim3(64), 0, stream, q, off_dw_w, off_dw_b, off_pw_w, vgrid);
    hipLaunchKernelGGL(k_sample, dim3(256), dim3(256), 0, stream, x, bn1_g, bn1_b, vgrid, kv);
    hipLaunchKernelGGL(k_kvconv, dim3(256), dim3(256), 0, stream, kv, kw, vw, kk, vv);
    hipLaunchKernelGGL(k_w2pack, dim3(64), dim3(256), 0, stream, cpb_w2, w2p);
    hipLaunchKernelGGL(k_cpb, dim3(2048), dim3(256), 0, stream,
                       vgrid, w2p, cpb_w1, cpb_b1, cpb_b2, cpb_w3, cpb_b3, biasb);
    hipLaunchKernelGGL(k_attn, dim3(256), dim3(256), 0, stream, q, kk, vv, biasb, ao);
    // out projection: M=512, K=512, B=ao (bf16), resid=x -> xo
    k_gemm<0, 512, 8, true, false><<<dim3(256), dim3(256), 0, stream>>>(
        out_w, ao, x, out_b, xo, nullptr, nullptr);
    // MLP1: M=2048, K=512, B=xo fp32 with BN2 folded, gelu -> h1o (bf16)
    k_gemm<1, 512, 32, false, true><<<dim3(1024), dim3(256), 0, stream>>>(
        mlp_w1, xo, nullptr, mlp_b1, h1o, bn2_g, bn2_b);
    // MLP2: M=512, K=2048, B=h1o bf16, resid=xo -> d_out
    k_gemm<2, 2048, 8, true, false><<<dim3(256), dim3(256), 0, stream>>>(
        mlp_w2, h1o, xo, mlp_b2, d_out, nullptr, nullptr);
}